// Round 11
// baseline (2927.870 us; speedup 1.0000x reference)
//
#include <hip/hip_runtime.h>
#include <hip/hip_bf16.h>

#define HID 128
#define EA_DIM 11
#define MSG_IN (2 * HID + EA_DIM)   // 267
#define TILE_E 128
#define KCAP 272                     // layer-1 K padded to 17*16
#define KB (KCAP * 2)                // 544 bytes per LDS row
#define MSG_LDS 102400               // A1/m union (69632) + A2 (32768)

typedef __attribute__((ext_vector_type(8))) short short8;
typedef __attribute__((ext_vector_type(16))) float f32x16;
typedef __attribute__((ext_vector_type(4))) float float4v;

__device__ __forceinline__ float siluf(float x) { return x / (1.f + __expf(-x)); }
__device__ __forceinline__ short f2bf(float f) {
    __hip_bfloat16 h = __float2bfloat16(f);
    return *reinterpret_cast<short*>(&h);
}
__device__ __forceinline__ int crow(int r, int khalf) { return (r & 3) + 8 * (r >> 2) + 4 * khalf; }

// A1-region address: row-stride 544B. BIJECTIVE swizzle: XOR bits[6:4] with a
// function of bits[9:7] of the LINEAR address (those bits are unchanged by the
// XOR => invertible; write & read both apply it => always consistent).
__device__ __forceinline__ int swa1(int row, int off) {
    int a = row * KB + off;
    return a ^ (((a >> 7) & 7) << 4);
}
// A2-region address: row-stride 256B, row-only XOR (R9-proven)
__device__ __forceinline__ int swa2(int row, int off) {
    return (row * 256 + off) ^ ((row & 7) << 4);
}

// ---------------- encoder ----------------
__global__ __launch_bounds__(128) void encoder_kernel(
    const float* __restrict__ x, const float* __restrict__ W1, const float* __restrict__ b1,
    const float* __restrict__ W2, const float* __restrict__ b2,
    float* __restrict__ h, short* __restrict__ hb)
{
    int i = blockIdx.x, j = threadIdx.x;
    __shared__ float xs[9];
    __shared__ float t1[HID];
    if (j < 9) xs[j] = x[(size_t)i * 9 + j];
    __syncthreads();
    float acc = b1[j];
    #pragma unroll
    for (int k = 0; k < 9; ++k) acc = fmaf(xs[k], W1[k * HID + j], acc);
    t1[j] = siluf(acc);
    __syncthreads();
    float acc2 = b2[j];
    #pragma unroll 8
    for (int k = 0; k < HID; ++k) acc2 = fmaf(t1[k], W2[k * HID + j], acc2);
    float v = siluf(acc2);
    h[(size_t)i * HID + j] = v;
    if (hb) hb[(size_t)i * HID + j] = f2bf(v);
}

// ---- one-time weight conversion to transposed bf16 layouts ----
__global__ void convert_w_kernel(
    const float* __restrict__ msgW1, const float* __restrict__ msgW2,
    const float* __restrict__ updW,
    const float* __restrict__ efW1, const float* __restrict__ efW2, const float* __restrict__ efW3,
    short* __restrict__ w1t, short* __restrict__ w2t, short* __restrict__ updwt,
    short* __restrict__ efw1t, short* __restrict__ efw2t, short* __restrict__ efw3t, int nl)
{
    int gid = blockIdx.x * blockDim.x + threadIdx.x;
    int n1 = nl * 128 * (KCAP / 8);
    int n2 = nl * 128 * (HID / 8);
    int n3 = nl * 128 * 32;
    int n4 = 64 * 32, n5 = 64 * 8, n6 = 32 * 8;
    short8 v;
    if (gid < n1) {
        int c = gid % (KCAP / 8);
        int rem = gid / (KCAP / 8);
        int n = rem % 128, lay = rem / 128;
        #pragma unroll
        for (int j = 0; j < 8; ++j) {
            int k = c * 8 + j;
            v[j] = (k < MSG_IN) ? f2bf(msgW1[(size_t)lay * MSG_IN * HID + (size_t)k * HID + n]) : (short)0;
        }
        *(short8*)(w1t + ((size_t)lay * 128 + n) * KCAP + c * 8) = v;
    } else if (gid < n1 + n2) {
        int g = gid - n1;
        int c = g % (HID / 8);
        int rem = g / (HID / 8);
        int n = rem % 128, lay = rem / 128;
        #pragma unroll
        for (int j = 0; j < 8; ++j)
            v[j] = f2bf(msgW2[(size_t)lay * HID * HID + (size_t)(c * 8 + j) * HID + n]);
        *(short8*)(w2t + ((size_t)lay * 128 + n) * HID + c * 8) = v;
    } else if (gid < n1 + n2 + n3) {
        int g = gid - n1 - n2;
        int c = g & 31;
        int rem = g >> 5;
        int n = rem & 127, lay = rem >> 7;
        #pragma unroll
        for (int j = 0; j < 8; ++j)
            v[j] = f2bf(updW[(size_t)lay * 256 * 128 + (size_t)(c * 8 + j) * 128 + n]);
        *(short8*)(updwt + ((size_t)lay * 128 + n) * 256 + c * 8) = v;
    } else if (gid < n1 + n2 + n3 + n4) {
        int g = gid - n1 - n2 - n3;
        int c = g & 31, n = g >> 5;
        #pragma unroll
        for (int j = 0; j < 8; ++j)
            v[j] = f2bf(efW1[(size_t)(c * 8 + j + 1) * 64 + n]);
        *(short8*)(efw1t + (size_t)n * 256 + c * 8) = v;
    } else if (gid < n1 + n2 + n3 + n4 + n5) {
        int g = gid - n1 - n2 - n3 - n4;
        int c = g & 7, n = g >> 3;
        #pragma unroll
        for (int j = 0; j < 8; ++j)
            v[j] = f2bf(efW2[(size_t)(c * 8 + j) * 64 + n]);
        *(short8*)(efw2t + (size_t)n * 64 + c * 8) = v;
    } else if (gid < n1 + n2 + n3 + n4 + n5 + n6) {
        int g = gid - n1 - n2 - n3 - n4 - n5;
        int c = g & 7, n = g >> 3;
        #pragma unroll
        for (int j = 0; j < 8; ++j)
            v[j] = (n < 3) ? f2bf(efW3[(size_t)(c * 8 + j) * 3 + n]) : (short)0;
        *(short8*)(efw3t + (size_t)n * 64 + c * 8) = v;
    }
}

// ---------------- CSR sort preprocessing ----------------
__global__ void hist_kernel(const int* __restrict__ ei, int* __restrict__ cnt, int E)
{
    for (int e = blockIdx.x * blockDim.x + threadIdx.x; e < E; e += gridDim.x * blockDim.x)
        atomicAdd(&cnt[ei[(size_t)E + e]], 1);
}
__global__ __launch_bounds__(256) void scanA_kernel(const int* __restrict__ cnt, int* __restrict__ btot, int N)
{
    __shared__ int s[256];
    int i = blockIdx.x * 256 + threadIdx.x;
    s[threadIdx.x] = (i < N) ? cnt[i] : 0;
    __syncthreads();
    for (int o = 128; o > 0; o >>= 1) {
        if (threadIdx.x < o) s[threadIdx.x] += s[threadIdx.x + o];
        __syncthreads();
    }
    if (threadIdx.x == 0) btot[blockIdx.x] = s[0];
}
__global__ __launch_bounds__(1024) void scanB_kernel(int* __restrict__ btot, int nb)
{
    __shared__ int s[1024];
    int t = threadIdx.x;
    int v = (t < nb) ? btot[t] : 0;
    s[t] = v;
    __syncthreads();
    for (int o = 1; o < 1024; o <<= 1) {
        int tv = 0;
        if (t >= o) tv = s[t - o];
        __syncthreads();
        s[t] += tv;
        __syncthreads();
    }
    if (t < nb) btot[t] = s[t] - v;   // exclusive
}
__global__ __launch_bounds__(256) void scanC_kernel(const int* __restrict__ cnt, const int* __restrict__ btot,
                                                    int* __restrict__ cur, int N)
{
    __shared__ int s[256];
    int i = blockIdx.x * 256 + threadIdx.x;
    int t = threadIdx.x;
    int v = (i < N) ? cnt[i] : 0;
    s[t] = v;
    __syncthreads();
    for (int o = 1; o < 256; o <<= 1) {
        int tv = 0;
        if (t >= o) tv = s[t - o];
        __syncthreads();
        s[t] += tv;
        __syncthreads();
    }
    if (i < N) cur[i] = btot[blockIdx.x] + s[t] - v;   // exclusive start
}
__global__ void scatter_kernel(const int* __restrict__ ei, int* __restrict__ cur,
                               int* __restrict__ eord, int E)
{
    for (int e = blockIdx.x * blockDim.x + threadIdx.x; e < E; e += gridDim.x * blockDim.x) {
        int d = ei[(size_t)E + e];
        int p = atomicAdd(&cur[d], 1);
        eord[p] = e;
    }
}
__global__ void reorder_kernel(const int* __restrict__ ei, const float* __restrict__ ea,
                               const int* __restrict__ eord,
                               int* __restrict__ srcs_s, int* __restrict__ dsts_s,
                               short* __restrict__ ea_s, int E)
{
    for (int p = blockIdx.x * blockDim.x + threadIdx.x; p < E; p += gridDim.x * blockDim.x) {
        int es = eord[p];
        srcs_s[p] = ei[es];
        dsts_s[p] = ei[(size_t)E + es];
        short tv[16];
        #pragma unroll
        for (int j = 0; j < 16; ++j) tv[j] = 0;
        #pragma unroll
        for (int j = 0; j < EA_DIM; ++j) tv[j] = f2bf(ea[(size_t)es * EA_DIM + j]);
        short8 v0, v1;
        #pragma unroll
        for (int j = 0; j < 8; ++j) { v0[j] = tv[j]; v1[j] = tv[8 + j]; }
        *(short8*)(ea_s + (size_t)p * 16) = v0;
        *(short8*)(ea_s + (size_t)p * 16 + 8) = v1;
    }
}

// ======== MFMA message kernel: 512 thr, W1 fragment in REGISTERS, 4 barriers/tile,
// ======== bijective address-swizzle, sorted streams + LDS reduce, reg-prefetch
__global__ __launch_bounds__(512, 2) void msg_mfma_kernel(
    const float* __restrict__ h, const short* __restrict__ hb,
    const int* __restrict__ ei, const float* __restrict__ ea,
    const int* __restrict__ srcs_s, const int* __restrict__ dsts_s, const short* __restrict__ ea_s,
    const short* __restrict__ w1t, const float* __restrict__ b1,
    const short* __restrict__ w2t, const float* __restrict__ b2,
    float* __restrict__ agg, int E, int ntiles)
{
    extern __shared__ char smem[];       // [A1/m union 69632 | A2 32768]
    char* sA2r = smem + 69632;
    __shared__ int dsts[TILE_E];

    int tid = threadIdx.x, ln = tid & 63, wave = tid >> 6;
    int mh = wave & 1, nq4 = wave >> 1;        // 2 (M) x 4 (N) waves
    int l31 = ln & 31, khalf = ln >> 5;

    int col = nq4 * 32 + l31;                  // this wave's output column
    float b1v = b1[col], b2v = b2[col];
    short8 zer;
    #pragma unroll
    for (int j = 0; j < 8; ++j) zer[j] = 0;
    int ar0 = mh * 64 + l31;                   // A rows (and +32)
    const short8* w2r = (const short8*)(w2t + (size_t)col * HID);

    // ---- W1 fragment resident in registers (68 VGPR/lane, loaded once) ----
    short8 w1f[17];
    {
        const short8* w1r = (const short8*)(w1t + (size_t)col * KCAP);
        #pragma unroll
        for (int kk = 0; kk < 17; ++kk) w1f[kk] = w1r[kk * 2 + khalf];
    }

    bool sorted = (ea_s != nullptr) && (hb != nullptr);

    // ---- prefetch state (sorted path): 4 threads per edge row ----
    int pr = tid >> 2, pq = tid & 3;
    int pf_idx = 0; bool pf_valid = false;
    short8 pf_h[8];
    short8 pf_e0 = zer, pf_e1 = zer;

    if (sorted) {
        long ep = (long)blockIdx.x * TILE_E + pr;
        pf_valid = ep < E;
        pf_idx = pf_valid ? ((pq < 2) ? srcs_s[ep] : dsts_s[ep]) : 0;
        const short8* hr8 = (const short8*)(hb + (size_t)pf_idx * HID + (pq & 1) * 64);
        #pragma unroll
        for (int c = 0; c < 8; ++c) pf_h[c] = hr8[c];
        if (pq == 3 && pf_valid) {
            pf_e0 = *(const short8*)(ea_s + (size_t)ep * 16);
            pf_e1 = *(const short8*)(ea_s + (size_t)ep * 16 + 8);
        }
    }

    #pragma unroll 1
    for (int tile = blockIdx.x; tile < ntiles; tile += gridDim.x) {
        __syncthreads();   // b0: prior-iter region0 reads (segreduce) done

        if (sorted) {
            // ---- write prefetched tile -> LDS ----
            int dbase = (pq >> 1) * 256 + (pq & 1) * 128;
            #pragma unroll
            for (int c = 0; c < 8; ++c) {
                short8 v = pf_valid ? pf_h[c] : zer;
                *(short8*)(smem + swa1(pr, dbase + c * 16)) = v;
            }
            if (pq == 2) dsts[pr] = pf_valid ? pf_idx : -1;
            if (pq == 3) {
                *(short8*)(smem + swa1(pr, 512)) = pf_valid ? pf_e0 : zer;
                *(short8*)(smem + swa1(pr, 528)) = pf_valid ? pf_e1 : zer;
            }
        } else {
            int r = pr, q = pq;
            long ep = (long)tile * TILE_E + r;
            bool valid = ep < E;
            int idx = 0;
            if (valid) idx = (q < 2) ? ei[ep] : ei[(size_t)E + ep];
            int half = q & 1;
            int dbase = (q >> 1) * 256 + half * 128;
            if (hb) {
                const short8* hr8 = (const short8*)(hb + (size_t)idx * HID + half * 64);
                #pragma unroll
                for (int c = 0; c < 8; ++c) {
                    short8 v = valid ? hr8[c] : zer;
                    *(short8*)(smem + swa1(r, dbase + c * 16)) = v;
                }
            } else {
                const float* hr = h + (size_t)idx * HID + half * 64;
                #pragma unroll
                for (int c = 0; c < 8; ++c) {
                    short8 v = zer;
                    if (valid) {
                        float4v f0 = *(const float4v*)(hr + c * 8);
                        float4v f1 = *(const float4v*)(hr + c * 8 + 4);
                        #pragma unroll
                        for (int j = 0; j < 4; ++j) { v[j] = f2bf(f0[j]); v[4 + j] = f2bf(f1[j]); }
                    }
                    *(short8*)(smem + swa1(r, dbase + c * 16)) = v;
                }
            }
            if (q == 2) dsts[r] = valid ? idx : -1;
            if (q == 3) {
                short8 v0 = zer, v1 = zer;
                if (valid) {
                    short tv[16];
                    #pragma unroll
                    for (int j = 0; j < 16; ++j) tv[j] = 0;
                    #pragma unroll
                    for (int j = 0; j < EA_DIM; ++j) tv[j] = f2bf(ea[(size_t)ep * EA_DIM + j]);
                    #pragma unroll
                    for (int j = 0; j < 8; ++j) { v0[j] = tv[j]; v1[j] = tv[8 + j]; }
                }
                *(short8*)(smem + swa1(r, 512)) = v0;
                *(short8*)(smem + swa1(r, 528)) = v1;
            }
        }
        __syncthreads();   // b1: A1 staged

        if (sorted) {
            // ---- issue NEXT tile's gather (latency hides under MFMA phases) ----
            long ep = (long)(tile + gridDim.x) * TILE_E + pr;
            pf_valid = ep < E;
            pf_idx = pf_valid ? ((pq < 2) ? srcs_s[ep] : dsts_s[ep]) : 0;
            const short8* hr8 = (const short8*)(hb + (size_t)pf_idx * HID + (pq & 1) * 64);
            #pragma unroll
            for (int c = 0; c < 8; ++c) pf_h[c] = hr8[c];
            if (pq == 3 && pf_valid) {
                pf_e0 = *(const short8*)(ea_s + (size_t)ep * 16);
                pf_e1 = *(const short8*)(ea_s + (size_t)ep * 16 + 8);
            }
        }

        // ---- layer 1: wave computes 64 rows x 32 cols; B from registers ----
        f32x16 acc1[2] = {};
        #pragma unroll
        for (int kk = 0; kk < 17; ++kk) {
            int kb = kk * 32 + khalf * 16;
            short8 a0 = *(short8*)(smem + swa1(ar0, kb));
            short8 a1 = *(short8*)(smem + swa1(ar0 + 32, kb));
            acc1[0] = __builtin_amdgcn_mfma_f32_32x32x16_bf16(a0, w1f[kk], acc1[0], 0, 0, 0);
            acc1[1] = __builtin_amdgcn_mfma_f32_32x32x16_bf16(a1, w1f[kk], acc1[1], 0, 0, 0);
        }

        // ---- bias + silu -> A2 (disjoint region: no barrier needed after L1) ----
        #pragma unroll
        for (int mi = 0; mi < 2; ++mi)
            #pragma unroll
            for (int r = 0; r < 16; ++r) {
                float s = siluf(acc1[mi][r] + b1v);
                int row = mh * 64 + mi * 32 + crow(r, khalf);
                *(short*)(sA2r + swa2(row, col * 2)) = f2bf(s);
            }
        __syncthreads();   // b2: A2 visible (also: all L1 A1-reads complete)

        // ---- layer 2: B from global w2t (L1-resident, 32 KB) ----
        f32x16 acc2[2];
        #pragma unroll
        for (int mi = 0; mi < 2; ++mi)
            #pragma unroll
            for (int r = 0; r < 16; ++r) acc2[mi][r] = b2v;
        #pragma unroll
        for (int kk = 0; kk < 8; ++kk) {
            int kb = kk * 32 + khalf * 16;
            short8 a0 = *(short8*)(sA2r + swa2(ar0, kb));
            short8 a1 = *(short8*)(sA2r + swa2(ar0 + 32, kb));
            short8 w  = w2r[kk * 2 + khalf];
            acc2[0] = __builtin_amdgcn_mfma_f32_32x32x16_bf16(a0, w, acc2[0], 0, 0, 0);
            acc2[1] = __builtin_amdgcn_mfma_f32_32x32x16_bf16(a1, w, acc2[1], 0, 0, 0);
        }

        if (sorted) {
            // ---- m -> region0 f32 [128][128] (A1 dead since b2; no barrier needed) ----
            #pragma unroll
            for (int mi = 0; mi < 2; ++mi)
                #pragma unroll
                for (int r = 0; r < 16; ++r) {
                    int row = mh * 64 + mi * 32 + crow(r, khalf);
                    *(float*)(smem + row * 512 + col * 4) = acc2[mi][r];
                }
            __syncthreads();   // b3: m visible
            // ---- segmented reduce: thread = (col pair, 16-row group) ----
            {
                int c2 = tid & 63, g = tid >> 6;
                float s0 = 0.f, s1 = 0.f;
                int dprev = -1;
                #pragma unroll 1
                for (int rr = 0; rr < 16; ++rr) {
                    int row = g * 16 + rr;
                    int d = dsts[row];
                    float2 v = *(float2*)(smem + row * 512 + c2 * 8);
                    if (d != dprev) {
                        if (dprev >= 0) {
                            atomicAdd(agg + (size_t)dprev * HID + c2 * 2,     s0);
                            atomicAdd(agg + (size_t)dprev * HID + c2 * 2 + 1, s1);
                        }
                        s0 = 0.f; s1 = 0.f; dprev = d;
                    }
                    if (d >= 0) { s0 += v.x; s1 += v.y; }
                }
                if (dprev >= 0) {
                    atomicAdd(agg + (size_t)dprev * HID + c2 * 2,     s0);
                    atomicAdd(agg + (size_t)dprev * HID + c2 * 2 + 1, s1);
                }
            }
        } else {
            // ---- fallback: direct atomic scatter ----
            #pragma unroll
            for (int mi = 0; mi < 2; ++mi)
                #pragma unroll
                for (int r = 0; r < 16; ++r) {
                    int row = mh * 64 + mi * 32 + crow(r, khalf);
                    int d = dsts[row];
                    if (d >= 0) atomicAdd(agg + (size_t)d * HID + col, acc2[mi][r]);
                }
        }
    }
}

// ---------------- MFMA update kernel ----------------
__global__ __launch_bounds__(256) void upd_mfma_kernel(
    float* __restrict__ h, short* __restrict__ hb, const float* __restrict__ agg,
    const short* __restrict__ updwt, const float* __restrict__ b, int N, int ntiles)
{
    __shared__ char sA[64 * 512];
    int tid = threadIdx.x, ln = tid & 63, wave = tid >> 6;
    int mhalf = wave & 1, nhalf = wave >> 1, l31 = ln & 31, khalf = ln >> 5;
    float bv[2];
    #pragma unroll
    for (int ni = 0; ni < 2; ++ni) bv[ni] = b[nhalf * 64 + ni * 32 + l31];
    short8 zer;
    #pragma unroll
    for (int j = 0; j < 8; ++j) zer[j] = 0;

    #pragma unroll 1
    for (int tile = blockIdx.x; tile < ntiles; tile += gridDim.x) {
        __syncthreads();
        {
            int r = tid >> 2, q = tid & 3;
            int node = tile * 64 + r;
            bool valid = node < N;
            if (q < 2) {
                if (hb) {
                    const short8* hr8 = (const short8*)(hb + (size_t)node * HID + (q & 1) * 64);
                    #pragma unroll
                    for (int c = 0; c < 8; ++c) {
                        short8 v = valid ? hr8[c] : zer;
                        *(short8*)(sA + ((r * 512 + (q & 1) * 128 + c * 16) ^ ((r & 7) << 4))) = v;
                    }
                } else {
                    const float* hr = h + (size_t)node * HID + (q & 1) * 64;
                    #pragma unroll
                    for (int c = 0; c < 8; ++c) {
                        short8 v = zer;
                        if (valid) {
                            float4v f0 = *(const float4v*)(hr + c * 8);
                            float4v f1 = *(const float4v*)(hr + c * 8 + 4);
                            #pragma unroll
                            for (int j = 0; j < 4; ++j) { v[j] = f2bf(f0[j]); v[4 + j] = f2bf(f1[j]); }
                        }
                        *(short8*)(sA + ((r * 512 + (q & 1) * 128 + c * 16) ^ ((r & 7) << 4))) = v;
                    }
                }
            } else {
                const float* ar = agg + (size_t)node * HID + (q & 1) * 64;
                #pragma unroll
                for (int c = 0; c < 8; ++c) {
                    short8 v = zer;
                    if (valid) {
                        float4v f0 = *(const float4v*)(ar + c * 8);
                        float4v f1 = *(const float4v*)(ar + c * 8 + 4);
                        #pragma unroll
                        for (int j = 0; j < 4; ++j) { v[j] = f2bf(f0[j]); v[4 + j] = f2bf(f1[j]); }
                    }
                    *(short8*)(sA + ((r * 512 + 256 + (q & 1) * 128 + c * 16) ^ ((r & 7) << 4))) = v;
                }
            }
        }
        __syncthreads();
        f32x16 acc[2] = {};
        int arow = mhalf * 32 + l31;
        const short* bp0 = updwt + (size_t)(nhalf * 64 + l31) * 256 + khalf * 8;
        const short* bp1 = updwt + (size_t)(nhalf * 64 + 32 + l31) * 256 + khalf * 8;
        for (int kk = 0; kk < 16; ++kk) {
            short8 a  = *(short8*)(sA + ((arow * 512 + kk * 32 + khalf * 16) ^ ((arow & 7) << 4)));
            short8 w0 = *(const short8*)(bp0 + kk * 16);
            short8 w1 = *(const short8*)(bp1 + kk * 16);
            acc[0] = __builtin_amdgcn_mfma_f32_32x32x16_bf16(a, w0, acc[0], 0, 0, 0);
            acc[1] = __builtin_amdgcn_mfma_f32_32x32x16_bf16(a, w1, acc[1], 0, 0, 0);
        }
        #pragma unroll
        for (int ni = 0; ni < 2; ++ni) {
            int col = nhalf * 64 + ni * 32 + l31;
            #pragma unroll
            for (int r = 0; r < 16; ++r) {
                int node = tile * 64 + mhalf * 32 + crow(r, khalf);
                if (node < N) {
                    float val = siluf(acc[ni][r] + bv[ni] + h[(size_t)node * HID + col]);
                    h[(size_t)node * HID + col] = val;
                    if (hb) hb[(size_t)node * HID + col] = f2bf(val);
                }
            }
        }
    }
}

// ---------------- MFMA edge-fields kernel ----------------
__global__ __launch_bounds__(256) void fields_mfma_kernel(
    const float* __restrict__ h, const short* __restrict__ hb,
    const int* __restrict__ conn, const float* __restrict__ bc,
    const float* __restrict__ efW1, const float* __restrict__ efb1,
    const float* __restrict__ efb2, const float* __restrict__ efb3,
    const short* __restrict__ efw1t, const short* __restrict__ efw2t, const short* __restrict__ efw3t,
    float* __restrict__ f_out, int EC, int nq, int ntiles)
{
    __shared__ char sA1[64 * 512];
    __shared__ char sA2[64 * 128];
    __shared__ char sF2[64 * 128];
    __shared__ float bcis[64], bcjs[64];
    int tid = threadIdx.x, ln = tid & 63, wave = tid >> 6;
    int mhalf = wave & 1, nhalf = wave >> 1, l31 = ln & 31, khalf = ln >> 5;
    int col = nhalf * 32 + l31;
    float w1x = efW1[col];
    float b1v = efb1[col], b2v = efb2[col];
    float b3v = (l31 < 3) ? efb3[l31] : 0.f;
    float inv = (nq > 1) ? 1.f / (float)(nq - 1) : 0.f;
    short8 zer;
    #pragma unroll
    for (int j = 0; j < 8; ++j) zer[j] = 0;

    #pragma unroll 1
    for (int tile = blockIdx.x; tile < ntiles; tile += gridDim.x) {
        __syncthreads();
        {
            int r = tid >> 2, q = tid & 3;
            long p = (long)tile * 64 + r;
            bool valid = p < EC;
            int node = 0;
            if (valid) node = conn[p * 2 + (q >> 1)];
            if (q == 0) {
                bcis[r] = valid ? bc[conn[p * 2]] : 0.f;
                bcjs[r] = valid ? bc[conn[p * 2 + 1]] : 0.f;
            }
            int cbyte = (q >> 1) * 256 + (q & 1) * 128;
            if (hb) {
                const short8* hr8 = (const short8*)(hb + (size_t)node * HID + (q & 1) * 64);
                #pragma unroll
                for (int c = 0; c < 8; ++c) {
                    short8 v = valid ? hr8[c] : zer;
                    *(short8*)(sA1 + ((r * 512 + cbyte + c * 16) ^ ((r & 7) << 4))) = v;
                }
            } else {
                const float* hr = h + (size_t)node * HID + (q & 1) * 64;
                #pragma unroll
                for (int c = 0; c < 8; ++c) {
                    short8 v = zer;
                    if (valid) {
                        float4v f0 = *(const float4v*)(hr + c * 8);
                        float4v f1 = *(const float4v*)(hr + c * 8 + 4);
                        #pragma unroll
                        for (int j = 0; j < 4; ++j) { v[j] = f2bf(f0[j]); v[4 + j] = f2bf(f1[j]); }
                    }
                    *(short8*)(sA1 + ((r * 512 + cbyte + c * 16) ^ ((r & 7) << 4))) = v;
                }
            }
        }
        __syncthreads();
        f32x16 hp = {};
        int arow = mhalf * 32 + l31;
        for (int kk = 0; kk < 16; ++kk) {
            short8 a = *(short8*)(sA1 + ((arow * 512 + kk * 32 + khalf * 16) ^ ((arow & 7) << 4)));
            short8 b = *(const short8*)(efw1t + (size_t)col * 256 + kk * 16 + khalf * 8);
            hp = __builtin_amdgcn_mfma_f32_32x32x16_bf16(a, b, hp, 0, 0, 0);
        }
        #pragma unroll
        for (int r = 0; r < 16; ++r) hp[r] += b1v;

        for (int q = 0; q < nq; ++q) {
            float xi = (float)q * inv;
            #pragma unroll
            for (int r = 0; r < 16; ++r) {
                float f1 = siluf(fmaf(xi, w1x, hp[r]));
                int row = mhalf * 32 + crow(r, khalf);
                *(short*)(sA2 + ((row * 128 + col * 2) ^ ((row & 7) << 4))) = f2bf(f1);
            }
            __syncthreads();
            f32x16 f2a = {};
            for (int kk = 0; kk < 4; ++kk) {
                short8 a = *(short8*)(sA2 + ((arow * 128 + kk * 32 + khalf * 16) ^ ((l31 & 7) << 4)));
                short8 b = *(const short8*)(efw2t + (size_t)col * 64 + kk * 16 + khalf * 8);
                f2a = __builtin_amdgcn_mfma_f32_32x32x16_bf16(a, b, f2a, 0, 0, 0);
            }
            #pragma unroll
            for (int r = 0; r < 16; ++r) {
                float f2 = siluf(f2a[r] + b2v);
                int row = mhalf * 32 + crow(r, khalf);
                *(short*)(sF2 + ((row * 128 + col * 2) ^ ((row & 7) << 4))) = f2bf(f2);
            }
            __syncthreads();
            f32x16 oa = {};
            for (int kk = 0; kk < 4; ++kk) {
                short8 a = *(short8*)(sF2 + ((arow * 128 + kk * 32 + khalf * 16) ^ ((l31 & 7) << 4)));
                short8 b = *(const short8*)(efw3t + (size_t)l31 * 64 + kk * 16 + khalf * 8);
                oa = __builtin_amdgcn_mfma_f32_32x32x16_bf16(a, b, oa, 0, 0, 0);
            }
            if (nhalf == 0 && l31 < 3) {
                #pragma unroll
                for (int r = 0; r < 16; ++r) {
                    int row = mhalf * 32 + crow(r, khalf);
                    long p = (long)tile * 64 + row;
                    if (p < EC) {
                        float mask = (1.f - bcis[row] * (1.f - xi)) * (1.f - bcjs[row] * xi);
                        f_out[((size_t)p * nq + q) * 3 + l31] = (oa[r] + b3v) * mask;
                    }
                }
            }
        }
    }
}

// ---------------- aux: prop passthrough + xi fill ----------------
__global__ void aux_kernel(const float* __restrict__ prop, float* __restrict__ out_p,
                           float* __restrict__ out_xi, int EC, int nq, float inv)
{
    int i = blockIdx.x * blockDim.x + threadIdx.x;
    if (i < EC) out_p[i] = prop[i];
    if (i < EC * nq) out_xi[i] = (float)(i % nq) * inv;
}

extern "C" void kernel_launch(void* const* d_in, const int* in_sizes, int n_in,
                              void* d_out, int out_size, void* d_ws, size_t ws_size,
                              hipStream_t stream) {
    const float* x     = (const float*)d_in[0];
    const int*   ei    = (const int*)d_in[1];
    const float* ea    = (const float*)d_in[2];
    const int*   conn  = (const int*)d_in[3];
    const float* bc    = (const float*)d_in[4];
    const float* prop  = (const float*)d_in[5];
    const float* encW1 = (const float*)d_in[7];
    const float* encb1 = (const float*)d_in[8];
    const float* encW2 = (const float*)d_in[9];
    const float* encb2 = (const float*)d_in[10];
    const float* msgW1 = (const float*)d_in[11];
    const float* msgb1 = (const float*)d_in[12];
    const float* msgW2 = (const float*)d_in[13];
    const float* msgb2 = (const float*)d_in[14];
    const float* updW  = (const float*)d_in[15];
    const float* updb  = (const float*)d_in[16];
    const float* efW1  = (const float*)d_in[17];
    const float* efb1  = (const float*)d_in[18];
    const float* efW2  = (const float*)d_in[19];
    const float* efb2  = (const float*)d_in[20];
    const float* efW3  = (const float*)d_in[21];
    const float* efb3  = (const float*)d_in[22];

    int N  = in_sizes[0] / 9;
    int E  = in_sizes[1] / 2;
    int EC = in_sizes[5];
    int nl = in_sizes[11] / (MSG_IN * HID);
    int nq = (int)(((long long)out_size - (long long)N * HID - EC) / (4LL * EC));

    float* out    = (float*)d_out;
    float* h      = out;
    float* out_xi = out + (size_t)N * HID;
    float* out_f  = out_xi + (size_t)EC * nq;
    float* out_p  = out_f + (size_t)EC * nq * 3;

    // ws: [weights][hb][agg][icnt N][icur N][btot 1024][eord E][srcs_s E][dsts_s E][ea_s 16E]
    size_t w1t_e = (size_t)nl * 128 * KCAP;
    size_t w2t_e = (size_t)nl * 128 * HID;
    size_t updwt_e = (size_t)nl * 128 * 256;
    size_t efw1t_e = 64 * 256, efw2t_e = 64 * 64, efw3t_e = 32 * 64;
    short* w1t   = (short*)d_ws;
    short* w2t   = w1t + w1t_e;
    short* updwt = w2t + w2t_e;
    short* efw1t = updwt + updwt_e;
    short* efw2t = efw1t + efw1t_e;
    short* efw3t = efw2t + efw2t_e;
    size_t wbytes = (w1t_e + w2t_e + updwt_e + efw1t_e + efw2t_e + efw3t_e) * 2;
    wbytes = (wbytes + 255) & ~(size_t)255;
    size_t hb_bytes  = (size_t)N * HID * 2;
    size_t agg_bytes = (size_t)N * HID * 4;
    size_t sort_bytes = ((size_t)2 * N + 1024 + (size_t)3 * E) * 4 + (size_t)E * 32;

    short* hb = nullptr;
    float* agg;
    int *icnt = nullptr, *icur = nullptr, *btot = nullptr, *eord = nullptr;
    int *srcs_s = nullptr, *dsts_s = nullptr;
    short* ea_s = nullptr;
    if (ws_size >= wbytes + hb_bytes + agg_bytes + sort_bytes) {
        char* p = (char*)d_ws + wbytes;
        hb = (short*)p;      p += hb_bytes;
        agg = (float*)p;     p += agg_bytes;
        icnt = (int*)p;      p += (size_t)N * 4;
        icur = (int*)p;      p += (size_t)N * 4;
        btot = (int*)p;      p += 1024 * 4;
        eord = (int*)p;      p += (size_t)E * 4;
        srcs_s = (int*)p;    p += (size_t)E * 4;
        dsts_s = (int*)p;    p += (size_t)E * 4;
        ea_s = (short*)p;
    } else if (ws_size >= wbytes + hb_bytes + agg_bytes) {
        hb  = (short*)((char*)d_ws + wbytes);
        agg = (float*)((char*)d_ws + wbytes + hb_bytes);
    } else {
        agg = (float*)((char*)d_ws + wbytes);
    }

    hipFuncSetAttribute((const void*)msg_mfma_kernel,
                        hipFuncAttributeMaxDynamicSharedMemorySize, MSG_LDS);

    encoder_kernel<<<N, 128, 0, stream>>>(x, encW1, encb1, encW2, encb2, h, hb);

    {
        int chunks = nl * 128 * (KCAP / 8) + nl * 128 * (HID / 8) + nl * 128 * 32
                   + 64 * 32 + 64 * 8 + 32 * 8;
        convert_w_kernel<<<(chunks + 255) / 256, 256, 0, stream>>>(
            msgW1, msgW2, updW, efW1, efW2, efW3,
            w1t, w2t, updwt, efw1t, efw2t, efw3t, nl);
    }

    if (ea_s) {
        int nb = (N + 255) / 256;
        hipMemsetAsync(icnt, 0, (size_t)N * 4, stream);
        hist_kernel<<<512, 256, 0, stream>>>(ei, icnt, E);
        scanA_kernel<<<nb, 256, 0, stream>>>(icnt, btot, N);
        scanB_kernel<<<1, 1024, 0, stream>>>(btot, nb);
        scanC_kernel<<<nb, 256, 0, stream>>>(icnt, btot, icur, N);
        scatter_kernel<<<512, 256, 0, stream>>>(ei, icur, eord, E);
        reorder_kernel<<<512, 256, 0, stream>>>(ei, ea, eord, srcs_s, dsts_s, ea_s, E);
    }

    int ntiles = (E + TILE_E - 1) / TILE_E;
    int utiles = (N + 63) / 64;
    for (int l = 0; l < nl; ++l) {
        hipMemsetAsync(agg, 0, agg_bytes, stream);
        msg_mfma_kernel<<<256, 512, MSG_LDS, stream>>>(
            h, hb, ei, ea, srcs_s, dsts_s, ea_s,
            w1t + (size_t)l * 128 * KCAP, msgb1 + (size_t)l * HID,
            w2t + (size_t)l * 128 * HID,  msgb2 + (size_t)l * HID,
            agg, E, ntiles);
        upd_mfma_kernel<<<512, 256, 0, stream>>>(
            h, hb, agg, updwt + (size_t)l * 128 * 256, updb + (size_t)l * HID, N, utiles);
    }

    int ftiles = (EC + 63) / 64;
    fields_mfma_kernel<<<512, 256, 0, stream>>>(
        h, hb, conn, bc, efW1, efb1, efb2, efb3, efw1t, efw2t, efw3t,
        out_f, EC, nq, ftiles);

    float inv = (nq > 1) ? 1.f / (float)(nq - 1) : 0.f;
    aux_kernel<<<(EC * nq + 255) / 256, 256, 0, stream>>>(prop, out_p, out_xi, EC, nq, inv);
}

// Round 12
// 2917.752 us; speedup vs baseline: 1.0035x; 1.0035x over previous
//
#include <hip/hip_runtime.h>
#include <hip/hip_bf16.h>

#define HID 128
#define EA_DIM 11
#define MSG_IN (2 * HID + EA_DIM)   // 267
#define TILE_E 128
#define KCAP 272                     // layer-1 K padded to 17*16
#define KB (KCAP * 2)                // 544 bytes per LDS row
#define MSG_LDS 102400               // A1/m union (69632) + A2 (32768)

typedef __attribute__((ext_vector_type(8))) short short8;
typedef __attribute__((ext_vector_type(16))) float f32x16;
typedef __attribute__((ext_vector_type(4))) float float4v;

__device__ __forceinline__ float siluf(float x) { return x / (1.f + __expf(-x)); }
__device__ __forceinline__ short f2bf(float f) {
    __hip_bfloat16 h = __float2bfloat16(f);
    return *reinterpret_cast<short*>(&h);
}
__device__ __forceinline__ int crow(int r, int khalf) { return (r & 3) + 8 * (r >> 2) + 4 * khalf; }

// A1-region address: row-stride 544B. BIJECTIVE swizzle: XOR bits[6:4] with a
// function of bits[9:7] of the LINEAR address (those bits are unchanged by the
// XOR => invertible; write & read both apply it => always consistent).
__device__ __forceinline__ int swa1(int row, int off) {
    int a = row * KB + off;
    return a ^ (((a >> 7) & 7) << 4);
}
// A2-region address: row-stride 256B, row-only XOR (R9-proven)
__device__ __forceinline__ int swa2(int row, int off) {
    return (row * 256 + off) ^ ((row & 7) << 4);
}

// ---------------- encoder ----------------
__global__ __launch_bounds__(128) void encoder_kernel(
    const float* __restrict__ x, const float* __restrict__ W1, const float* __restrict__ b1,
    const float* __restrict__ W2, const float* __restrict__ b2,
    float* __restrict__ h, short* __restrict__ hb)
{
    int i = blockIdx.x, j = threadIdx.x;
    __shared__ float xs[9];
    __shared__ float t1[HID];
    if (j < 9) xs[j] = x[(size_t)i * 9 + j];
    __syncthreads();
    float acc = b1[j];
    #pragma unroll
    for (int k = 0; k < 9; ++k) acc = fmaf(xs[k], W1[k * HID + j], acc);
    t1[j] = siluf(acc);
    __syncthreads();
    float acc2 = b2[j];
    #pragma unroll 8
    for (int k = 0; k < HID; ++k) acc2 = fmaf(t1[k], W2[k * HID + j], acc2);
    float v = siluf(acc2);
    h[(size_t)i * HID + j] = v;
    if (hb) hb[(size_t)i * HID + j] = f2bf(v);
}

// ---- one-time weight conversion to transposed bf16 layouts ----
__global__ void convert_w_kernel(
    const float* __restrict__ msgW1, const float* __restrict__ msgW2,
    const float* __restrict__ updW,
    const float* __restrict__ efW1, const float* __restrict__ efW2, const float* __restrict__ efW3,
    short* __restrict__ w1t, short* __restrict__ w2t, short* __restrict__ updwt,
    short* __restrict__ efw1t, short* __restrict__ efw2t, short* __restrict__ efw3t, int nl)
{
    int gid = blockIdx.x * blockDim.x + threadIdx.x;
    int n1 = nl * 128 * (KCAP / 8);
    int n2 = nl * 128 * (HID / 8);
    int n3 = nl * 128 * 32;
    int n4 = 64 * 32, n5 = 64 * 8, n6 = 32 * 8;
    short8 v;
    if (gid < n1) {
        int c = gid % (KCAP / 8);
        int rem = gid / (KCAP / 8);
        int n = rem % 128, lay = rem / 128;
        #pragma unroll
        for (int j = 0; j < 8; ++j) {
            int k = c * 8 + j;
            v[j] = (k < MSG_IN) ? f2bf(msgW1[(size_t)lay * MSG_IN * HID + (size_t)k * HID + n]) : (short)0;
        }
        *(short8*)(w1t + ((size_t)lay * 128 + n) * KCAP + c * 8) = v;
    } else if (gid < n1 + n2) {
        int g = gid - n1;
        int c = g % (HID / 8);
        int rem = g / (HID / 8);
        int n = rem % 128, lay = rem / 128;
        #pragma unroll
        for (int j = 0; j < 8; ++j)
            v[j] = f2bf(msgW2[(size_t)lay * HID * HID + (size_t)(c * 8 + j) * HID + n]);
        *(short8*)(w2t + ((size_t)lay * 128 + n) * HID + c * 8) = v;
    } else if (gid < n1 + n2 + n3) {
        int g = gid - n1 - n2;
        int c = g & 31;
        int rem = g >> 5;
        int n = rem & 127, lay = rem >> 7;
        #pragma unroll
        for (int j = 0; j < 8; ++j)
            v[j] = f2bf(updW[(size_t)lay * 256 * 128 + (size_t)(c * 8 + j) * 128 + n]);
        *(short8*)(updwt + ((size_t)lay * 128 + n) * 256 + c * 8) = v;
    } else if (gid < n1 + n2 + n3 + n4) {
        int g = gid - n1 - n2 - n3;
        int c = g & 31, n = g >> 5;
        #pragma unroll
        for (int j = 0; j < 8; ++j)
            v[j] = f2bf(efW1[(size_t)(c * 8 + j + 1) * 64 + n]);
        *(short8*)(efw1t + (size_t)n * 256 + c * 8) = v;
    } else if (gid < n1 + n2 + n3 + n4 + n5) {
        int g = gid - n1 - n2 - n3 - n4;
        int c = g & 7, n = g >> 3;
        #pragma unroll
        for (int j = 0; j < 8; ++j)
            v[j] = f2bf(efW2[(size_t)(c * 8 + j) * 64 + n]);
        *(short8*)(efw2t + (size_t)n * 64 + c * 8) = v;
    } else if (gid < n1 + n2 + n3 + n4 + n5 + n6) {
        int g = gid - n1 - n2 - n3 - n4 - n5;
        int c = g & 7, n = g >> 3;
        #pragma unroll
        for (int j = 0; j < 8; ++j)
            v[j] = (n < 3) ? f2bf(efW3[(size_t)(c * 8 + j) * 3 + n]) : (short)0;
        *(short8*)(efw3t + (size_t)n * 64 + c * 8) = v;
    }
}

// ---------------- CSR sort preprocessing ----------------
__global__ void hist_kernel(const int* __restrict__ ei, int* __restrict__ cnt, int E)
{
    for (int e = blockIdx.x * blockDim.x + threadIdx.x; e < E; e += gridDim.x * blockDim.x)
        atomicAdd(&cnt[ei[(size_t)E + e]], 1);
}
__global__ __launch_bounds__(256) void scanA_kernel(const int* __restrict__ cnt, int* __restrict__ btot, int N)
{
    __shared__ int s[256];
    int i = blockIdx.x * 256 + threadIdx.x;
    s[threadIdx.x] = (i < N) ? cnt[i] : 0;
    __syncthreads();
    for (int o = 128; o > 0; o >>= 1) {
        if (threadIdx.x < o) s[threadIdx.x] += s[threadIdx.x + o];
        __syncthreads();
    }
    if (threadIdx.x == 0) btot[blockIdx.x] = s[0];
}
__global__ __launch_bounds__(1024) void scanB_kernel(int* __restrict__ btot, int nb)
{
    __shared__ int s[1024];
    int t = threadIdx.x;
    int v = (t < nb) ? btot[t] : 0;
    s[t] = v;
    __syncthreads();
    for (int o = 1; o < 1024; o <<= 1) {
        int tv = 0;
        if (t >= o) tv = s[t - o];
        __syncthreads();
        s[t] += tv;
        __syncthreads();
    }
    if (t < nb) btot[t] = s[t] - v;   // exclusive
}
__global__ __launch_bounds__(256) void scanC_kernel(const int* __restrict__ cnt, const int* __restrict__ btot,
                                                    int* __restrict__ cur, int N)
{
    __shared__ int s[256];
    int i = blockIdx.x * 256 + threadIdx.x;
    int t = threadIdx.x;
    int v = (i < N) ? cnt[i] : 0;
    s[t] = v;
    __syncthreads();
    for (int o = 1; o < 256; o <<= 1) {
        int tv = 0;
        if (t >= o) tv = s[t - o];
        __syncthreads();
        s[t] += tv;
        __syncthreads();
    }
    if (i < N) cur[i] = btot[blockIdx.x] + s[t] - v;   // exclusive start
}
__global__ void scatter_kernel(const int* __restrict__ ei, int* __restrict__ cur,
                               int* __restrict__ eord, int E)
{
    for (int e = blockIdx.x * blockDim.x + threadIdx.x; e < E; e += gridDim.x * blockDim.x) {
        int d = ei[(size_t)E + e];
        int p = atomicAdd(&cur[d], 1);
        eord[p] = e;
    }
}
__global__ void reorder_kernel(const int* __restrict__ ei, const float* __restrict__ ea,
                               const int* __restrict__ eord,
                               int* __restrict__ srcs_s, int* __restrict__ dsts_s,
                               short* __restrict__ ea_s, int E)
{
    for (int p = blockIdx.x * blockDim.x + threadIdx.x; p < E; p += gridDim.x * blockDim.x) {
        int es = eord[p];
        srcs_s[p] = ei[es];
        dsts_s[p] = ei[(size_t)E + es];
        short tv[16];
        #pragma unroll
        for (int j = 0; j < 16; ++j) tv[j] = 0;
        #pragma unroll
        for (int j = 0; j < EA_DIM; ++j) tv[j] = f2bf(ea[(size_t)es * EA_DIM + j]);
        short8 v0, v1;
        #pragma unroll
        for (int j = 0; j < 8; ++j) { v0[j] = tv[j]; v1[j] = tv[8 + j]; }
        *(short8*)(ea_s + (size_t)p * 16) = v0;
        *(short8*)(ea_s + (size_t)p * 16 + 8) = v1;
    }
}

// ======== MFMA message kernel: 512 thr, W1 fragment in REGISTERS, 4 barriers/tile,
// ======== bijective address-swizzle, sorted streams + LDS reduce, reg-prefetch.
// ======== __launch_bounds__(512,1): block is LDS-capped to 1/CU anyway; allows
// ======== up to 256 VGPR so the W1 fragment (68 regs) does NOT spill (R11 bug).
__global__ __launch_bounds__(512, 1) void msg_mfma_kernel(
    const float* __restrict__ h, const short* __restrict__ hb,
    const int* __restrict__ ei, const float* __restrict__ ea,
    const int* __restrict__ srcs_s, const int* __restrict__ dsts_s, const short* __restrict__ ea_s,
    const short* __restrict__ w1t, const float* __restrict__ b1,
    const short* __restrict__ w2t, const float* __restrict__ b2,
    float* __restrict__ agg, int E, int ntiles)
{
    extern __shared__ char smem[];       // [A1/m union 69632 | A2 32768]
    char* sA2r = smem + 69632;
    __shared__ int dsts[TILE_E];

    int tid = threadIdx.x, ln = tid & 63, wave = tid >> 6;
    int mh = wave & 1, nq4 = wave >> 1;        // 2 (M) x 4 (N) waves
    int l31 = ln & 31, khalf = ln >> 5;

    int col = nq4 * 32 + l31;                  // this wave's output column
    float b1v = b1[col], b2v = b2[col];
    short8 zer;
    #pragma unroll
    for (int j = 0; j < 8; ++j) zer[j] = 0;
    int ar0 = mh * 64 + l31;                   // A rows (and +32)
    const short8* w2r = (const short8*)(w2t + (size_t)col * HID);

    // ---- W1 fragment resident in registers (68 VGPR/lane, loaded once) ----
    short8 w1f[17];
    {
        const short8* w1r = (const short8*)(w1t + (size_t)col * KCAP);
        #pragma unroll
        for (int kk = 0; kk < 17; ++kk) w1f[kk] = w1r[kk * 2 + khalf];
    }

    bool sorted = (ea_s != nullptr) && (hb != nullptr);

    // ---- prefetch state (sorted path): 4 threads per edge row ----
    int pr = tid >> 2, pq = tid & 3;
    int pf_idx = 0; bool pf_valid = false;
    short8 pf_h[8];
    short8 pf_e0 = zer, pf_e1 = zer;

    if (sorted) {
        long ep = (long)blockIdx.x * TILE_E + pr;
        pf_valid = ep < E;
        pf_idx = pf_valid ? ((pq < 2) ? srcs_s[ep] : dsts_s[ep]) : 0;
        const short8* hr8 = (const short8*)(hb + (size_t)pf_idx * HID + (pq & 1) * 64);
        #pragma unroll
        for (int c = 0; c < 8; ++c) pf_h[c] = hr8[c];
        if (pq == 3 && pf_valid) {
            pf_e0 = *(const short8*)(ea_s + (size_t)ep * 16);
            pf_e1 = *(const short8*)(ea_s + (size_t)ep * 16 + 8);
        }
    }

    #pragma unroll 1
    for (int tile = blockIdx.x; tile < ntiles; tile += gridDim.x) {
        __syncthreads();   // b0: prior-iter region0 reads (segreduce) done

        if (sorted) {
            // ---- write prefetched tile -> LDS ----
            int dbase = (pq >> 1) * 256 + (pq & 1) * 128;
            #pragma unroll
            for (int c = 0; c < 8; ++c) {
                short8 v = pf_valid ? pf_h[c] : zer;
                *(short8*)(smem + swa1(pr, dbase + c * 16)) = v;
            }
            if (pq == 2) dsts[pr] = pf_valid ? pf_idx : -1;
            if (pq == 3) {
                *(short8*)(smem + swa1(pr, 512)) = pf_valid ? pf_e0 : zer;
                *(short8*)(smem + swa1(pr, 528)) = pf_valid ? pf_e1 : zer;
            }
        } else {
            int r = pr, q = pq;
            long ep = (long)tile * TILE_E + r;
            bool valid = ep < E;
            int idx = 0;
            if (valid) idx = (q < 2) ? ei[ep] : ei[(size_t)E + ep];
            int half = q & 1;
            int dbase = (q >> 1) * 256 + half * 128;
            if (hb) {
                const short8* hr8 = (const short8*)(hb + (size_t)idx * HID + half * 64);
                #pragma unroll
                for (int c = 0; c < 8; ++c) {
                    short8 v = valid ? hr8[c] : zer;
                    *(short8*)(smem + swa1(r, dbase + c * 16)) = v;
                }
            } else {
                const float* hr = h + (size_t)idx * HID + half * 64;
                #pragma unroll
                for (int c = 0; c < 8; ++c) {
                    short8 v = zer;
                    if (valid) {
                        float4v f0 = *(const float4v*)(hr + c * 8);
                        float4v f1 = *(const float4v*)(hr + c * 8 + 4);
                        #pragma unroll
                        for (int j = 0; j < 4; ++j) { v[j] = f2bf(f0[j]); v[4 + j] = f2bf(f1[j]); }
                    }
                    *(short8*)(smem + swa1(r, dbase + c * 16)) = v;
                }
            }
            if (q == 2) dsts[r] = valid ? idx : -1;
            if (q == 3) {
                short8 v0 = zer, v1 = zer;
                if (valid) {
                    short tv[16];
                    #pragma unroll
                    for (int j = 0; j < 16; ++j) tv[j] = 0;
                    #pragma unroll
                    for (int j = 0; j < EA_DIM; ++j) tv[j] = f2bf(ea[(size_t)ep * EA_DIM + j]);
                    #pragma unroll
                    for (int j = 0; j < 8; ++j) { v0[j] = tv[j]; v1[j] = tv[8 + j]; }
                }
                *(short8*)(smem + swa1(r, 512)) = v0;
                *(short8*)(smem + swa1(r, 528)) = v1;
            }
        }
        __syncthreads();   // b1: A1 staged

        if (sorted) {
            // ---- issue NEXT tile's gather (latency hides under MFMA phases) ----
            long ep = (long)(tile + gridDim.x) * TILE_E + pr;
            pf_valid = ep < E;
            pf_idx = pf_valid ? ((pq < 2) ? srcs_s[ep] : dsts_s[ep]) : 0;
            const short8* hr8 = (const short8*)(hb + (size_t)pf_idx * HID + (pq & 1) * 64);
            #pragma unroll
            for (int c = 0; c < 8; ++c) pf_h[c] = hr8[c];
            if (pq == 3 && pf_valid) {
                pf_e0 = *(const short8*)(ea_s + (size_t)ep * 16);
                pf_e1 = *(const short8*)(ea_s + (size_t)ep * 16 + 8);
            }
        }

        // ---- layer 1: wave computes 64 rows x 32 cols; B from registers ----
        f32x16 acc1[2] = {};
        #pragma unroll
        for (int kk = 0; kk < 17; ++kk) {
            int kb = kk * 32 + khalf * 16;
            short8 a0 = *(short8*)(smem + swa1(ar0, kb));
            short8 a1 = *(short8*)(smem + swa1(ar0 + 32, kb));
            acc1[0] = __builtin_amdgcn_mfma_f32_32x32x16_bf16(a0, w1f[kk], acc1[0], 0, 0, 0);
            acc1[1] = __builtin_amdgcn_mfma_f32_32x32x16_bf16(a1, w1f[kk], acc1[1], 0, 0, 0);
        }

        // ---- bias + silu -> A2 (disjoint region: no barrier needed after L1) ----
        #pragma unroll
        for (int mi = 0; mi < 2; ++mi)
            #pragma unroll
            for (int r = 0; r < 16; ++r) {
                float s = siluf(acc1[mi][r] + b1v);
                int row = mh * 64 + mi * 32 + crow(r, khalf);
                *(short*)(sA2r + swa2(row, col * 2)) = f2bf(s);
            }
        __syncthreads();   // b2: A2 visible (also: all L1 A1-reads complete)

        // ---- layer 2: B from global w2t (L1-resident, 32 KB) ----
        f32x16 acc2[2];
        #pragma unroll
        for (int mi = 0; mi < 2; ++mi)
            #pragma unroll
            for (int r = 0; r < 16; ++r) acc2[mi][r] = b2v;
        #pragma unroll
        for (int kk = 0; kk < 8; ++kk) {
            int kb = kk * 32 + khalf * 16;
            short8 a0 = *(short8*)(sA2r + swa2(ar0, kb));
            short8 a1 = *(short8*)(sA2r + swa2(ar0 + 32, kb));
            short8 w  = w2r[kk * 2 + khalf];
            acc2[0] = __builtin_amdgcn_mfma_f32_32x32x16_bf16(a0, w, acc2[0], 0, 0, 0);
            acc2[1] = __builtin_amdgcn_mfma_f32_32x32x16_bf16(a1, w, acc2[1], 0, 0, 0);
        }

        if (sorted) {
            // ---- m -> region0 f32 [128][128] (A1 dead since b2; no barrier needed) ----
            #pragma unroll
            for (int mi = 0; mi < 2; ++mi)
                #pragma unroll
                for (int r = 0; r < 16; ++r) {
                    int row = mh * 64 + mi * 32 + crow(r, khalf);
                    *(float*)(smem + row * 512 + col * 4) = acc2[mi][r];
                }
            __syncthreads();   // b3: m visible
            // ---- segmented reduce: thread = (col pair, 16-row group) ----
            {
                int c2 = tid & 63, g = tid >> 6;
                float s0 = 0.f, s1 = 0.f;
                int dprev = -1;
                #pragma unroll 1
                for (int rr = 0; rr < 16; ++rr) {
                    int row = g * 16 + rr;
                    int d = dsts[row];
                    float2 v = *(float2*)(smem + row * 512 + c2 * 8);
                    if (d != dprev) {
                        if (dprev >= 0) {
                            atomicAdd(agg + (size_t)dprev * HID + c2 * 2,     s0);
                            atomicAdd(agg + (size_t)dprev * HID + c2 * 2 + 1, s1);
                        }
                        s0 = 0.f; s1 = 0.f; dprev = d;
                    }
                    if (d >= 0) { s0 += v.x; s1 += v.y; }
                }
                if (dprev >= 0) {
                    atomicAdd(agg + (size_t)dprev * HID + c2 * 2,     s0);
                    atomicAdd(agg + (size_t)dprev * HID + c2 * 2 + 1, s1);
                }
            }
        } else {
            // ---- fallback: direct atomic scatter ----
            #pragma unroll
            for (int mi = 0; mi < 2; ++mi)
                #pragma unroll
                for (int r = 0; r < 16; ++r) {
                    int row = mh * 64 + mi * 32 + crow(r, khalf);
                    int d = dsts[row];
                    if (d >= 0) atomicAdd(agg + (size_t)d * HID + col, acc2[mi][r]);
                }
        }
    }
}

// ---------------- MFMA update kernel ----------------
__global__ __launch_bounds__(256) void upd_mfma_kernel(
    float* __restrict__ h, short* __restrict__ hb, const float* __restrict__ agg,
    const short* __restrict__ updwt, const float* __restrict__ b, int N, int ntiles)
{
    __shared__ char sA[64 * 512];
    int tid = threadIdx.x, ln = tid & 63, wave = tid >> 6;
    int mhalf = wave & 1, nhalf = wave >> 1, l31 = ln & 31, khalf = ln >> 5;
    float bv[2];
    #pragma unroll
    for (int ni = 0; ni < 2; ++ni) bv[ni] = b[nhalf * 64 + ni * 32 + l31];
    short8 zer;
    #pragma unroll
    for (int j = 0; j < 8; ++j) zer[j] = 0;

    #pragma unroll 1
    for (int tile = blockIdx.x; tile < ntiles; tile += gridDim.x) {
        __syncthreads();
        {
            int r = tid >> 2, q = tid & 3;
            int node = tile * 64 + r;
            bool valid = node < N;
            if (q < 2) {
                if (hb) {
                    const short8* hr8 = (const short8*)(hb + (size_t)node * HID + (q & 1) * 64);
                    #pragma unroll
                    for (int c = 0; c < 8; ++c) {
                        short8 v = valid ? hr8[c] : zer;
                        *(short8*)(sA + ((r * 512 + (q & 1) * 128 + c * 16) ^ ((r & 7) << 4))) = v;
                    }
                } else {
                    const float* hr = h + (size_t)node * HID + (q & 1) * 64;
                    #pragma unroll
                    for (int c = 0; c < 8; ++c) {
                        short8 v = zer;
                        if (valid) {
                            float4v f0 = *(const float4v*)(hr + c * 8);
                            float4v f1 = *(const float4v*)(hr + c * 8 + 4);
                            #pragma unroll
                            for (int j = 0; j < 4; ++j) { v[j] = f2bf(f0[j]); v[4 + j] = f2bf(f1[j]); }
                        }
                        *(short8*)(sA + ((r * 512 + (q & 1) * 128 + c * 16) ^ ((r & 7) << 4))) = v;
                    }
                }
            } else {
                const float* ar = agg + (size_t)node * HID + (q & 1) * 64;
                #pragma unroll
                for (int c = 0; c < 8; ++c) {
                    short8 v = zer;
                    if (valid) {
                        float4v f0 = *(const float4v*)(ar + c * 8);
                        float4v f1 = *(const float4v*)(ar + c * 8 + 4);
                        #pragma unroll
                        for (int j = 0; j < 4; ++j) { v[j] = f2bf(f0[j]); v[4 + j] = f2bf(f1[j]); }
                    }
                    *(short8*)(sA + ((r * 512 + 256 + (q & 1) * 128 + c * 16) ^ ((r & 7) << 4))) = v;
                }
            }
        }
        __syncthreads();
        f32x16 acc[2] = {};
        int arow = mhalf * 32 + l31;
        const short* bp0 = updwt + (size_t)(nhalf * 64 + l31) * 256 + khalf * 8;
        const short* bp1 = updwt + (size_t)(nhalf * 64 + 32 + l31) * 256 + khalf * 8;
        for (int kk = 0; kk < 16; ++kk) {
            short8 a  = *(short8*)(sA + ((arow * 512 + kk * 32 + khalf * 16) ^ ((arow & 7) << 4)));
            short8 w0 = *(const short8*)(bp0 + kk * 16);
            short8 w1 = *(const short8*)(bp1 + kk * 16);
            acc[0] = __builtin_amdgcn_mfma_f32_32x32x16_bf16(a, w0, acc[0], 0, 0, 0);
            acc[1] = __builtin_amdgcn_mfma_f32_32x32x16_bf16(a, w1, acc[1], 0, 0, 0);
        }
        #pragma unroll
        for (int ni = 0; ni < 2; ++ni) {
            int col = nhalf * 64 + ni * 32 + l31;
            #pragma unroll
            for (int r = 0; r < 16; ++r) {
                int node = tile * 64 + mhalf * 32 + crow(r, khalf);
                if (node < N) {
                    float val = siluf(acc[ni][r] + bv[ni] + h[(size_t)node * HID + col]);
                    h[(size_t)node * HID + col] = val;
                    if (hb) hb[(size_t)node * HID + col] = f2bf(val);
                }
            }
        }
    }
}

// ---------------- MFMA edge-fields kernel ----------------
__global__ __launch_bounds__(256) void fields_mfma_kernel(
    const float* __restrict__ h, const short* __restrict__ hb,
    const int* __restrict__ conn, const float* __restrict__ bc,
    const float* __restrict__ efW1, const float* __restrict__ efb1,
    const float* __restrict__ efb2, const float* __restrict__ efb3,
    const short* __restrict__ efw1t, const short* __restrict__ efw2t, const short* __restrict__ efw3t,
    float* __restrict__ f_out, int EC, int nq, int ntiles)
{
    __shared__ char sA1[64 * 512];
    __shared__ char sA2[64 * 128];
    __shared__ char sF2[64 * 128];
    __shared__ float bcis[64], bcjs[64];
    int tid = threadIdx.x, ln = tid & 63, wave = tid >> 6;
    int mhalf = wave & 1, nhalf = wave >> 1, l31 = ln & 31, khalf = ln >> 5;
    int col = nhalf * 32 + l31;
    float w1x = efW1[col];
    float b1v = efb1[col], b2v = efb2[col];
    float b3v = (l31 < 3) ? efb3[l31] : 0.f;
    float inv = (nq > 1) ? 1.f / (float)(nq - 1) : 0.f;
    short8 zer;
    #pragma unroll
    for (int j = 0; j < 8; ++j) zer[j] = 0;

    #pragma unroll 1
    for (int tile = blockIdx.x; tile < ntiles; tile += gridDim.x) {
        __syncthreads();
        {
            int r = tid >> 2, q = tid & 3;
            long p = (long)tile * 64 + r;
            bool valid = p < EC;
            int node = 0;
            if (valid) node = conn[p * 2 + (q >> 1)];
            if (q == 0) {
                bcis[r] = valid ? bc[conn[p * 2]] : 0.f;
                bcjs[r] = valid ? bc[conn[p * 2 + 1]] : 0.f;
            }
            int cbyte = (q >> 1) * 256 + (q & 1) * 128;
            if (hb) {
                const short8* hr8 = (const short8*)(hb + (size_t)node * HID + (q & 1) * 64);
                #pragma unroll
                for (int c = 0; c < 8; ++c) {
                    short8 v = valid ? hr8[c] : zer;
                    *(short8*)(sA1 + ((r * 512 + cbyte + c * 16) ^ ((r & 7) << 4))) = v;
                }
            } else {
                const float* hr = h + (size_t)node * HID + (q & 1) * 64;
                #pragma unroll
                for (int c = 0; c < 8; ++c) {
                    short8 v = zer;
                    if (valid) {
                        float4v f0 = *(const float4v*)(hr + c * 8);
                        float4v f1 = *(const float4v*)(hr + c * 8 + 4);
                        #pragma unroll
                        for (int j = 0; j < 4; ++j) { v[j] = f2bf(f0[j]); v[4 + j] = f2bf(f1[j]); }
                    }
                    *(short8*)(sA1 + ((r * 512 + cbyte + c * 16) ^ ((r & 7) << 4))) = v;
                }
            }
        }
        __syncthreads();
        f32x16 hp = {};
        int arow = mhalf * 32 + l31;
        for (int kk = 0; kk < 16; ++kk) {
            short8 a = *(short8*)(sA1 + ((arow * 512 + kk * 32 + khalf * 16) ^ ((arow & 7) << 4)));
            short8 b = *(const short8*)(efw1t + (size_t)col * 256 + kk * 16 + khalf * 8);
            hp = __builtin_amdgcn_mfma_f32_32x32x16_bf16(a, b, hp, 0, 0, 0);
        }
        #pragma unroll
        for (int r = 0; r < 16; ++r) hp[r] += b1v;

        for (int q = 0; q < nq; ++q) {
            float xi = (float)q * inv;
            #pragma unroll
            for (int r = 0; r < 16; ++r) {
                float f1 = siluf(fmaf(xi, w1x, hp[r]));
                int row = mhalf * 32 + crow(r, khalf);
                *(short*)(sA2 + ((row * 128 + col * 2) ^ ((row & 7) << 4))) = f2bf(f1);
            }
            __syncthreads();
            f32x16 f2a = {};
            for (int kk = 0; kk < 4; ++kk) {
                short8 a = *(short8*)(sA2 + ((arow * 128 + kk * 32 + khalf * 16) ^ ((l31 & 7) << 4)));
                short8 b = *(const short8*)(efw2t + (size_t)col * 64 + kk * 16 + khalf * 8);
                f2a = __builtin_amdgcn_mfma_f32_32x32x16_bf16(a, b, f2a, 0, 0, 0);
            }
            #pragma unroll
            for (int r = 0; r < 16; ++r) {
                float f2 = siluf(f2a[r] + b2v);
                int row = mhalf * 32 + crow(r, khalf);
                *(short*)(sF2 + ((row * 128 + col * 2) ^ ((row & 7) << 4))) = f2bf(f2);
            }
            __syncthreads();
            f32x16 oa = {};
            for (int kk = 0; kk < 4; ++kk) {
                short8 a = *(short8*)(sF2 + ((arow * 128 + kk * 32 + khalf * 16) ^ ((l31 & 7) << 4)));
                short8 b = *(const short8*)(efw3t + (size_t)l31 * 64 + kk * 16 + khalf * 8);
                oa = __builtin_amdgcn_mfma_f32_32x32x16_bf16(a, b, oa, 0, 0, 0);
            }
            if (nhalf == 0 && l31 < 3) {
                #pragma unroll
                for (int r = 0; r < 16; ++r) {
                    int row = mhalf * 32 + crow(r, khalf);
                    long p = (long)tile * 64 + row;
                    if (p < EC) {
                        float mask = (1.f - bcis[row] * (1.f - xi)) * (1.f - bcjs[row] * xi);
                        f_out[((size_t)p * nq + q) * 3 + l31] = (oa[r] + b3v) * mask;
                    }
                }
            }
        }
    }
}

// ---------------- aux: prop passthrough + xi fill ----------------
__global__ void aux_kernel(const float* __restrict__ prop, float* __restrict__ out_p,
                           float* __restrict__ out_xi, int EC, int nq, float inv)
{
    int i = blockIdx.x * blockDim.x + threadIdx.x;
    if (i < EC) out_p[i] = prop[i];
    if (i < EC * nq) out_xi[i] = (float)(i % nq) * inv;
}

extern "C" void kernel_launch(void* const* d_in, const int* in_sizes, int n_in,
                              void* d_out, int out_size, void* d_ws, size_t ws_size,
                              hipStream_t stream) {
    const float* x     = (const float*)d_in[0];
    const int*   ei    = (const int*)d_in[1];
    const float* ea    = (const float*)d_in[2];
    const int*   conn  = (const int*)d_in[3];
    const float* bc    = (const float*)d_in[4];
    const float* prop  = (const float*)d_in[5];
    const float* encW1 = (const float*)d_in[7];
    const float* encb1 = (const float*)d_in[8];
    const float* encW2 = (const float*)d_in[9];
    const float* encb2 = (const float*)d_in[10];
    const float* msgW1 = (const float*)d_in[11];
    const float* msgb1 = (const float*)d_in[12];
    const float* msgW2 = (const float*)d_in[13];
    const float* msgb2 = (const float*)d_in[14];
    const float* updW  = (const float*)d_in[15];
    const float* updb  = (const float*)d_in[16];
    const float* efW1  = (const float*)d_in[17];
    const float* efb1  = (const float*)d_in[18];
    const float* efW2  = (const float*)d_in[19];
    const float* efb2  = (const float*)d_in[20];
    const float* efW3  = (const float*)d_in[21];
    const float* efb3  = (const float*)d_in[22];

    int N  = in_sizes[0] / 9;
    int E  = in_sizes[1] / 2;
    int EC = in_sizes[5];
    int nl = in_sizes[11] / (MSG_IN * HID);
    int nq = (int)(((long long)out_size - (long long)N * HID - EC) / (4LL * EC));

    float* out    = (float*)d_out;
    float* h      = out;
    float* out_xi = out + (size_t)N * HID;
    float* out_f  = out_xi + (size_t)EC * nq;
    float* out_p  = out_f + (size_t)EC * nq * 3;

    // ws: [weights][hb][agg][icnt N][icur N][btot 1024][eord E][srcs_s E][dsts_s E][ea_s 16E]
    size_t w1t_e = (size_t)nl * 128 * KCAP;
    size_t w2t_e = (size_t)nl * 128 * HID;
    size_t updwt_e = (size_t)nl * 128 * 256;
    size_t efw1t_e = 64 * 256, efw2t_e = 64 * 64, efw3t_e = 32 * 64;
    short* w1t   = (short*)d_ws;
    short* w2t   = w1t + w1t_e;
    short* updwt = w2t + w2t_e;
    short* efw1t = updwt + updwt_e;
    short* efw2t = efw1t + efw1t_e;
    short* efw3t = efw2t + efw2t_e;
    size_t wbytes = (w1t_e + w2t_e + updwt_e + efw1t_e + efw2t_e + efw3t_e) * 2;
    wbytes = (wbytes + 255) & ~(size_t)255;
    size_t hb_bytes  = (size_t)N * HID * 2;
    size_t agg_bytes = (size_t)N * HID * 4;
    size_t sort_bytes = ((size_t)2 * N + 1024 + (size_t)3 * E) * 4 + (size_t)E * 32;

    short* hb = nullptr;
    float* agg;
    int *icnt = nullptr, *icur = nullptr, *btot = nullptr, *eord = nullptr;
    int *srcs_s = nullptr, *dsts_s = nullptr;
    short* ea_s = nullptr;
    if (ws_size >= wbytes + hb_bytes + agg_bytes + sort_bytes) {
        char* p = (char*)d_ws + wbytes;
        hb = (short*)p;      p += hb_bytes;
        agg = (float*)p;     p += agg_bytes;
        icnt = (int*)p;      p += (size_t)N * 4;
        icur = (int*)p;      p += (size_t)N * 4;
        btot = (int*)p;      p += 1024 * 4;
        eord = (int*)p;      p += (size_t)E * 4;
        srcs_s = (int*)p;    p += (size_t)E * 4;
        dsts_s = (int*)p;    p += (size_t)E * 4;
        ea_s = (short*)p;
    } else if (ws_size >= wbytes + hb_bytes + agg_bytes) {
        hb  = (short*)((char*)d_ws + wbytes);
        agg = (float*)((char*)d_ws + wbytes + hb_bytes);
    } else {
        agg = (float*)((char*)d_ws + wbytes);
    }

    hipFuncSetAttribute((const void*)msg_mfma_kernel,
                        hipFuncAttributeMaxDynamicSharedMemorySize, MSG_LDS);

    encoder_kernel<<<N, 128, 0, stream>>>(x, encW1, encb1, encW2, encb2, h, hb);

    {
        int chunks = nl * 128 * (KCAP / 8) + nl * 128 * (HID / 8) + nl * 128 * 32
                   + 64 * 32 + 64 * 8 + 32 * 8;
        convert_w_kernel<<<(chunks + 255) / 256, 256, 0, stream>>>(
            msgW1, msgW2, updW, efW1, efW2, efW3,
            w1t, w2t, updwt, efw1t, efw2t, efw3t, nl);
    }

    if (ea_s) {
        int nb = (N + 255) / 256;
        hipMemsetAsync(icnt, 0, (size_t)N * 4, stream);
        hist_kernel<<<512, 256, 0, stream>>>(ei, icnt, E);
        scanA_kernel<<<nb, 256, 0, stream>>>(icnt, btot, N);
        scanB_kernel<<<1, 1024, 0, stream>>>(btot, nb);
        scanC_kernel<<<nb, 256, 0, stream>>>(icnt, btot, icur, N);
        scatter_kernel<<<512, 256, 0, stream>>>(ei, icur, eord, E);
        reorder_kernel<<<512, 256, 0, stream>>>(ei, ea, eord, srcs_s, dsts_s, ea_s, E);
    }

    int ntiles = (E + TILE_E - 1) / TILE_E;
    int utiles = (N + 63) / 64;
    for (int l = 0; l < nl; ++l) {
        hipMemsetAsync(agg, 0, agg_bytes, stream);
        msg_mfma_kernel<<<256, 512, MSG_LDS, stream>>>(
            h, hb, ei, ea, srcs_s, dsts_s, ea_s,
            w1t + (size_t)l * 128 * KCAP, msgb1 + (size_t)l * HID,
            w2t + (size_t)l * 128 * HID,  msgb2 + (size_t)l * HID,
            agg, E, ntiles);
        upd_mfma_kernel<<<512, 256, 0, stream>>>(
            h, hb, agg, updwt + (size_t)l * 128 * 256, updb + (size_t)l * HID, N, utiles);
    }

    int ftiles = (EC + 63) / 64;
    fields_mfma_kernel<<<512, 256, 0, stream>>>(
        h, hb, conn, bc, efW1, efb1, efb2, efb3, efw1t, efw2t, efw3t,
        out_f, EC, nq, ftiles);

    float inv = (nq > 1) ? 1.f / (float)(nq - 1) : 0.f;
    aux_kernel<<<(EC * nq + 255) / 256, 256, 0, stream>>>(prop, out_p, out_xi, EC, nq, inv);
}

// Round 13
// 1754.117 us; speedup vs baseline: 1.6691x; 1.6634x over previous
//
#include <hip/hip_runtime.h>
#include <hip/hip_bf16.h>

#define HID 128
#define EA_DIM 11
#define MSG_IN (2 * HID + EA_DIM)   // 267
#define TILE_E 128
#define KCAP 272                     // layer-1 K padded to 17*16
#define KB (KCAP * 2)                // 544 bytes per LDS row
#define MSG_LDS 139264               // W1T (69632) + A1/A2/m union (69632)

typedef __attribute__((ext_vector_type(8))) short short8;
typedef __attribute__((ext_vector_type(16))) float f32x16;
typedef __attribute__((ext_vector_type(4))) float float4v;

__device__ __forceinline__ float siluf(float x) { return x / (1.f + __expf(-x)); }
__device__ __forceinline__ short f2bf(float f) {
    __hip_bfloat16 h = __float2bfloat16(f);
    return *reinterpret_cast<short*>(&h);
}
__device__ __forceinline__ int crow(int r, int khalf) { return (r & 3) + 8 * (r >> 2) + 4 * khalf; }

// BIJECTIVE linear-address swizzle: XOR bits[6:4] with bits[9:7] of the SAME
// address (bits>=7 unchanged => invertible within every 128B window; write and
// read both apply it => always consistent). Region base must be 128B-aligned.
__device__ __forceinline__ int swz(int a) { return a ^ (((a >> 7) & 7) << 4); }

// ---------------- encoder ----------------
__global__ __launch_bounds__(128) void encoder_kernel(
    const float* __restrict__ x, const float* __restrict__ W1, const float* __restrict__ b1,
    const float* __restrict__ W2, const float* __restrict__ b2,
    float* __restrict__ h, short* __restrict__ hb)
{
    int i = blockIdx.x, j = threadIdx.x;
    __shared__ float xs[9];
    __shared__ float t1[HID];
    if (j < 9) xs[j] = x[(size_t)i * 9 + j];
    __syncthreads();
    float acc = b1[j];
    #pragma unroll
    for (int k = 0; k < 9; ++k) acc = fmaf(xs[k], W1[k * HID + j], acc);
    t1[j] = siluf(acc);
    __syncthreads();
    float acc2 = b2[j];
    #pragma unroll 8
    for (int k = 0; k < HID; ++k) acc2 = fmaf(t1[k], W2[k * HID + j], acc2);
    float v = siluf(acc2);
    h[(size_t)i * HID + j] = v;
    if (hb) hb[(size_t)i * HID + j] = f2bf(v);
}

// ---- one-time weight conversion to transposed bf16 layouts ----
__global__ void convert_w_kernel(
    const float* __restrict__ msgW1, const float* __restrict__ msgW2,
    const float* __restrict__ updW,
    const float* __restrict__ efW1, const float* __restrict__ efW2, const float* __restrict__ efW3,
    short* __restrict__ w1t, short* __restrict__ w2t, short* __restrict__ updwt,
    short* __restrict__ efw1t, short* __restrict__ efw2t, short* __restrict__ efw3t, int nl)
{
    int gid = blockIdx.x * blockDim.x + threadIdx.x;
    int n1 = nl * 128 * (KCAP / 8);
    int n2 = nl * 128 * (HID / 8);
    int n3 = nl * 128 * 32;
    int n4 = 64 * 32, n5 = 64 * 8, n6 = 32 * 8;
    short8 v;
    if (gid < n1) {
        int c = gid % (KCAP / 8);
        int rem = gid / (KCAP / 8);
        int n = rem % 128, lay = rem / 128;
        #pragma unroll
        for (int j = 0; j < 8; ++j) {
            int k = c * 8 + j;
            v[j] = (k < MSG_IN) ? f2bf(msgW1[(size_t)lay * MSG_IN * HID + (size_t)k * HID + n]) : (short)0;
        }
        *(short8*)(w1t + ((size_t)lay * 128 + n) * KCAP + c * 8) = v;
    } else if (gid < n1 + n2) {
        int g = gid - n1;
        int c = g % (HID / 8);
        int rem = g / (HID / 8);
        int n = rem % 128, lay = rem / 128;
        #pragma unroll
        for (int j = 0; j < 8; ++j)
            v[j] = f2bf(msgW2[(size_t)lay * HID * HID + (size_t)(c * 8 + j) * HID + n]);
        *(short8*)(w2t + ((size_t)lay * 128 + n) * HID + c * 8) = v;
    } else if (gid < n1 + n2 + n3) {
        int g = gid - n1 - n2;
        int c = g & 31;
        int rem = g >> 5;
        int n = rem & 127, lay = rem >> 7;
        #pragma unroll
        for (int j = 0; j < 8; ++j)
            v[j] = f2bf(updW[(size_t)lay * 256 * 128 + (size_t)(c * 8 + j) * 128 + n]);
        *(short8*)(updwt + ((size_t)lay * 128 + n) * 256 + c * 8) = v;
    } else if (gid < n1 + n2 + n3 + n4) {
        int g = gid - n1 - n2 - n3;
        int c = g & 31, n = g >> 5;
        #pragma unroll
        for (int j = 0; j < 8; ++j)
            v[j] = f2bf(efW1[(size_t)(c * 8 + j + 1) * 64 + n]);
        *(short8*)(efw1t + (size_t)n * 256 + c * 8) = v;
    } else if (gid < n1 + n2 + n3 + n4 + n5) {
        int g = gid - n1 - n2 - n3 - n4;
        int c = g & 7, n = g >> 3;
        #pragma unroll
        for (int j = 0; j < 8; ++j)
            v[j] = f2bf(efW2[(size_t)(c * 8 + j) * 64 + n]);
        *(short8*)(efw2t + (size_t)n * 64 + c * 8) = v;
    } else if (gid < n1 + n2 + n3 + n4 + n5 + n6) {
        int g = gid - n1 - n2 - n3 - n4 - n5;
        int c = g & 7, n = g >> 3;
        #pragma unroll
        for (int j = 0; j < 8; ++j)
            v[j] = (n < 3) ? f2bf(efW3[(size_t)(c * 8 + j) * 3 + n]) : (short)0;
        *(short8*)(efw3t + (size_t)n * 64 + c * 8) = v;
    }
}

// ---------------- CSR sort preprocessing ----------------
__global__ void hist_kernel(const int* __restrict__ ei, int* __restrict__ cnt, int E)
{
    for (int e = blockIdx.x * blockDim.x + threadIdx.x; e < E; e += gridDim.x * blockDim.x)
        atomicAdd(&cnt[ei[(size_t)E + e]], 1);
}
__global__ __launch_bounds__(256) void scanA_kernel(const int* __restrict__ cnt, int* __restrict__ btot, int N)
{
    __shared__ int s[256];
    int i = blockIdx.x * 256 + threadIdx.x;
    s[threadIdx.x] = (i < N) ? cnt[i] : 0;
    __syncthreads();
    for (int o = 128; o > 0; o >>= 1) {
        if (threadIdx.x < o) s[threadIdx.x] += s[threadIdx.x + o];
        __syncthreads();
    }
    if (threadIdx.x == 0) btot[blockIdx.x] = s[0];
}
__global__ __launch_bounds__(1024) void scanB_kernel(int* __restrict__ btot, int nb)
{
    __shared__ int s[1024];
    int t = threadIdx.x;
    int v = (t < nb) ? btot[t] : 0;
    s[t] = v;
    __syncthreads();
    for (int o = 1; o < 1024; o <<= 1) {
        int tv = 0;
        if (t >= o) tv = s[t - o];
        __syncthreads();
        s[t] += tv;
        __syncthreads();
    }
    if (t < nb) btot[t] = s[t] - v;   // exclusive
}
__global__ __launch_bounds__(256) void scanC_kernel(const int* __restrict__ cnt, const int* __restrict__ btot,
                                                    int* __restrict__ cur, int N)
{
    __shared__ int s[256];
    int i = blockIdx.x * 256 + threadIdx.x;
    int t = threadIdx.x;
    int v = (i < N) ? cnt[i] : 0;
    s[t] = v;
    __syncthreads();
    for (int o = 1; o < 256; o <<= 1) {
        int tv = 0;
        if (t >= o) tv = s[t - o];
        __syncthreads();
        s[t] += tv;
        __syncthreads();
    }
    if (i < N) cur[i] = btot[blockIdx.x] + s[t] - v;   // exclusive start
}
__global__ void scatter_kernel(const int* __restrict__ ei, int* __restrict__ cur,
                               int* __restrict__ eord, int E)
{
    for (int e = blockIdx.x * blockDim.x + threadIdx.x; e < E; e += gridDim.x * blockDim.x) {
        int d = ei[(size_t)E + e];
        int p = atomicAdd(&cur[d], 1);
        eord[p] = e;
    }
}
__global__ void reorder_kernel(const int* __restrict__ ei, const float* __restrict__ ea,
                               const int* __restrict__ eord,
                               int* __restrict__ srcs_s, int* __restrict__ dsts_s,
                               short* __restrict__ ea_s, int E)
{
    for (int p = blockIdx.x * blockDim.x + threadIdx.x; p < E; p += gridDim.x * blockDim.x) {
        int es = eord[p];
        srcs_s[p] = ei[es];
        dsts_s[p] = ei[(size_t)E + es];
        short tv[16];
        #pragma unroll
        for (int j = 0; j < 16; ++j) tv[j] = 0;
        #pragma unroll
        for (int j = 0; j < EA_DIM; ++j) tv[j] = f2bf(ea[(size_t)es * EA_DIM + j]);
        short8 v0, v1;
        #pragma unroll
        for (int j = 0; j < 8; ++j) { v0[j] = tv[j]; v1[j] = tv[8 + j]; }
        *(short8*)(ea_s + (size_t)p * 16) = v0;
        *(short8*)(ea_s + (size_t)p * 16 + 8) = v1;
    }
}

// ======== MFMA message kernel (R9 structure): 512 thr, W1T in LDS, sorted
// ======== streams + LDS segreduce, reg-prefetch; NEW: bijective address
// ======== swizzle on W1T/A1 regions (kills 8-way staging + 4-way read conflicts)
__global__ __launch_bounds__(512, 1) void msg_mfma_kernel(
    const float* __restrict__ h, const short* __restrict__ hb,
    const int* __restrict__ ei, const float* __restrict__ ea,
    const int* __restrict__ srcs_s, const int* __restrict__ dsts_s, const short* __restrict__ ea_s,
    const short* __restrict__ w1t, const float* __restrict__ b1,
    const short* __restrict__ w2t, const float* __restrict__ b2,
    float* __restrict__ agg, int E, int ntiles)
{
    extern __shared__ char smem[];       // [W1T 69632 | A1/A2/m union 69632]
    char* sA = smem + 69632;
    __shared__ int dsts[TILE_E];

    int tid = threadIdx.x, ln = tid & 63, wave = tid >> 6;
    int mh = wave & 1, nq4 = wave >> 1;        // 2 (M) x 4 (N) waves
    int l31 = ln & 31, khalf = ln >> 5;

    // ---- stage W1T once per block (address-swizzled); covered by loop-top barrier ----
    {
        int row = tid & 127, grp = tid >> 7;
        for (int c = grp; c < 34; c += 4) {
            short8 v = *(const short8*)(w1t + (size_t)row * KCAP + c * 8);
            *(short8*)(smem + swz(row * KB + c * 16)) = v;
        }
    }

    int col = nq4 * 32 + l31;                  // this wave's output column
    float b1v = b1[col], b2v = b2[col];
    short8 zer;
    #pragma unroll
    for (int j = 0; j < 8; ++j) zer[j] = 0;
    int ar0 = mh * 64 + l31;                   // A rows (and +32)
    const short8* w2r = (const short8*)(w2t + (size_t)col * HID);

    bool sorted = (ea_s != nullptr) && (hb != nullptr);

    // ---- prefetch state (sorted path): 4 threads per edge row ----
    int pr = tid >> 2, pq = tid & 3;
    int pf_idx = 0; bool pf_valid = false;
    short8 pf_h[8];
    short8 pf_e0 = zer, pf_e1 = zer;

    if (sorted) {
        long ep = (long)blockIdx.x * TILE_E + pr;
        pf_valid = ep < E;
        pf_idx = pf_valid ? ((pq < 2) ? srcs_s[ep] : dsts_s[ep]) : 0;
        const short8* hr8 = (const short8*)(hb + (size_t)pf_idx * HID + (pq & 1) * 64);
        #pragma unroll
        for (int c = 0; c < 8; ++c) pf_h[c] = hr8[c];
        if (pq == 3 && pf_valid) {
            pf_e0 = *(const short8*)(ea_s + (size_t)ep * 16);
            pf_e1 = *(const short8*)(ea_s + (size_t)ep * 16 + 8);
        }
    }

    #pragma unroll 1
    for (int tile = blockIdx.x; tile < ntiles; tile += gridDim.x) {
        __syncthreads();   // prior-iter LDS reads done (covers W1T staging on iter 0)

        if (sorted) {
            // ---- write prefetched tile -> LDS (swizzled: conflict-free) ----
            int dbase = (pq >> 1) * 256 + (pq & 1) * 128;
            #pragma unroll
            for (int c = 0; c < 8; ++c) {
                short8 v = pf_valid ? pf_h[c] : zer;
                *(short8*)(sA + swz(pr * KB + dbase + c * 16)) = v;
            }
            if (pq == 2) dsts[pr] = pf_valid ? pf_idx : -1;
            if (pq == 3) {
                *(short8*)(sA + swz(pr * KB + 512)) = pf_valid ? pf_e0 : zer;
                *(short8*)(sA + swz(pr * KB + 528)) = pf_valid ? pf_e1 : zer;
            }
        } else {
            int r = pr, q = pq;
            long ep = (long)tile * TILE_E + r;
            bool valid = ep < E;
            int idx = 0;
            if (valid) idx = (q < 2) ? ei[ep] : ei[(size_t)E + ep];
            int half = q & 1;
            int dbase = (q >> 1) * 256 + half * 128;
            if (hb) {
                const short8* hr8 = (const short8*)(hb + (size_t)idx * HID + half * 64);
                #pragma unroll
                for (int c = 0; c < 8; ++c) {
                    short8 v = valid ? hr8[c] : zer;
                    *(short8*)(sA + swz(r * KB + dbase + c * 16)) = v;
                }
            } else {
                const float* hr = h + (size_t)idx * HID + half * 64;
                #pragma unroll
                for (int c = 0; c < 8; ++c) {
                    short8 v = zer;
                    if (valid) {
                        float4v f0 = *(const float4v*)(hr + c * 8);
                        float4v f1 = *(const float4v*)(hr + c * 8 + 4);
                        #pragma unroll
                        for (int j = 0; j < 4; ++j) { v[j] = f2bf(f0[j]); v[4 + j] = f2bf(f1[j]); }
                    }
                    *(short8*)(sA + swz(r * KB + dbase + c * 16)) = v;
                }
            }
            if (q == 2) dsts[r] = valid ? idx : -1;
            if (q == 3) {
                short8 v0 = zer, v1 = zer;
                if (valid) {
                    short tv[16];
                    #pragma unroll
                    for (int j = 0; j < 16; ++j) tv[j] = 0;
                    #pragma unroll
                    for (int j = 0; j < EA_DIM; ++j) tv[j] = f2bf(ea[(size_t)ep * EA_DIM + j]);
                    #pragma unroll
                    for (int j = 0; j < 8; ++j) { v0[j] = tv[j]; v1[j] = tv[8 + j]; }
                }
                *(short8*)(sA + swz(r * KB + 512)) = v0;
                *(short8*)(sA + swz(r * KB + 528)) = v1;
            }
        }
        __syncthreads();

        if (sorted) {
            // ---- issue NEXT tile's gather (latency hides under MFMA phases) ----
            long ep = (long)(tile + gridDim.x) * TILE_E + pr;
            pf_valid = ep < E;
            pf_idx = pf_valid ? ((pq < 2) ? srcs_s[ep] : dsts_s[ep]) : 0;
            const short8* hr8 = (const short8*)(hb + (size_t)pf_idx * HID + (pq & 1) * 64);
            #pragma unroll
            for (int c = 0; c < 8; ++c) pf_h[c] = hr8[c];
            if (pq == 3 && pf_valid) {
                pf_e0 = *(const short8*)(ea_s + (size_t)ep * 16);
                pf_e1 = *(const short8*)(ea_s + (size_t)ep * 16 + 8);
            }
        }

        // ---- layer 1: wave computes 64 rows x 32 cols; B from LDS W1T ----
        f32x16 acc1[2] = {};
        for (int kk = 0; kk < 17; ++kk) {
            int kb = kk * 32 + khalf * 16;
            short8 a0 = *(short8*)(sA + swz(ar0 * KB + kb));
            short8 a1 = *(short8*)(sA + swz((ar0 + 32) * KB + kb));
            short8 w  = *(short8*)(smem + swz(col * KB + kb));
            acc1[0] = __builtin_amdgcn_mfma_f32_32x32x16_bf16(a0, w, acc1[0], 0, 0, 0);
            acc1[1] = __builtin_amdgcn_mfma_f32_32x32x16_bf16(a1, w, acc1[1], 0, 0, 0);
        }
        __syncthreads();   // A1 reads done before A2 overwrite

        // ---- bias + silu -> A2 (bf16, 256B stride, R9-proven row swizzle) ----
        #pragma unroll
        for (int mi = 0; mi < 2; ++mi)
            #pragma unroll
            for (int r = 0; r < 16; ++r) {
                float s = siluf(acc1[mi][r] + b1v);
                int row = mh * 64 + mi * 32 + crow(r, khalf);
                *(short*)(sA + ((row * 256 + col * 2) ^ ((row & 7) << 4))) = f2bf(s);
            }
        __syncthreads();

        // ---- layer 2: B from global w2t (L1-resident, 32 KB) ----
        f32x16 acc2[2];
        #pragma unroll
        for (int mi = 0; mi < 2; ++mi)
            #pragma unroll
            for (int r = 0; r < 16; ++r) acc2[mi][r] = b2v;
        for (int kk = 0; kk < 8; ++kk) {
            int kb = kk * 32 + khalf * 16;
            short8 a0 = *(short8*)(sA + ((ar0 * 256 + kb) ^ ((ar0 & 7) << 4)));
            short8 a1 = *(short8*)(sA + (((ar0 + 32) * 256 + kb) ^ (((ar0 + 32) & 7) << 4)));
            short8 w  = w2r[kk * 2 + khalf];
            acc2[0] = __builtin_amdgcn_mfma_f32_32x32x16_bf16(a0, w, acc2[0], 0, 0, 0);
            acc2[1] = __builtin_amdgcn_mfma_f32_32x32x16_bf16(a1, w, acc2[1], 0, 0, 0);
        }

        if (sorted) {
            __syncthreads();   // A2 reads done before m overwrite
            // ---- m -> LDS f32 [128][128] ----
            #pragma unroll
            for (int mi = 0; mi < 2; ++mi)
                #pragma unroll
                for (int r = 0; r < 16; ++r) {
                    int row = mh * 64 + mi * 32 + crow(r, khalf);
                    *(float*)(sA + row * 512 + col * 4) = acc2[mi][r];
                }
            __syncthreads();
            // ---- segmented reduce: thread = (col pair, 16-row group) ----
            {
                int c2 = tid & 63, g = tid >> 6;
                float s0 = 0.f, s1 = 0.f;
                int dprev = -1;
                #pragma unroll 1
                for (int rr = 0; rr < 16; ++rr) {
                    int row = g * 16 + rr;
                    int d = dsts[row];
                    float2 v = *(float2*)(sA + row * 512 + c2 * 8);
                    if (d != dprev) {
                        if (dprev >= 0) {
                            atomicAdd(agg + (size_t)dprev * HID + c2 * 2,     s0);
                            atomicAdd(agg + (size_t)dprev * HID + c2 * 2 + 1, s1);
                        }
                        s0 = 0.f; s1 = 0.f; dprev = d;
                    }
                    if (d >= 0) { s0 += v.x; s1 += v.y; }
                }
                if (dprev >= 0) {
                    atomicAdd(agg + (size_t)dprev * HID + c2 * 2,     s0);
                    atomicAdd(agg + (size_t)dprev * HID + c2 * 2 + 1, s1);
                }
            }
        } else {
            // ---- fallback: direct atomic scatter ----
            #pragma unroll
            for (int mi = 0; mi < 2; ++mi)
                #pragma unroll
                for (int r = 0; r < 16; ++r) {
                    int row = mh * 64 + mi * 32 + crow(r, khalf);
                    int d = dsts[row];
                    if (d >= 0) atomicAdd(agg + (size_t)d * HID + col, acc2[mi][r]);
                }
        }
    }
}

// ---------------- MFMA update kernel ----------------
__global__ __launch_bounds__(256) void upd_mfma_kernel(
    float* __restrict__ h, short* __restrict__ hb, const float* __restrict__ agg,
    const short* __restrict__ updwt, const float* __restrict__ b, int N, int ntiles)
{
    __shared__ char sA[64 * 512];
    int tid = threadIdx.x, ln = tid & 63, wave = tid >> 6;
    int mhalf = wave & 1, nhalf = wave >> 1, l31 = ln & 31, khalf = ln >> 5;
    float bv[2];
    #pragma unroll
    for (int ni = 0; ni < 2; ++ni) bv[ni] = b[nhalf * 64 + ni * 32 + l31];
    short8 zer;
    #pragma unroll
    for (int j = 0; j < 8; ++j) zer[j] = 0;

    #pragma unroll 1
    for (int tile = blockIdx.x; tile < ntiles; tile += gridDim.x) {
        __syncthreads();
        {
            int r = tid >> 2, q = tid & 3;
            int node = tile * 64 + r;
            bool valid = node < N;
            if (q < 2) {
                if (hb) {
                    const short8* hr8 = (const short8*)(hb + (size_t)node * HID + (q & 1) * 64);
                    #pragma unroll
                    for (int c = 0; c < 8; ++c) {
                        short8 v = valid ? hr8[c] : zer;
                        *(short8*)(sA + ((r * 512 + (q & 1) * 128 + c * 16) ^ ((r & 7) << 4))) = v;
                    }
                } else {
                    const float* hr = h + (size_t)node * HID + (q & 1) * 64;
                    #pragma unroll
                    for (int c = 0; c < 8; ++c) {
                        short8 v = zer;
                        if (valid) {
                            float4v f0 = *(const float4v*)(hr + c * 8);
                            float4v f1 = *(const float4v*)(hr + c * 8 + 4);
                            #pragma unroll
                            for (int j = 0; j < 4; ++j) { v[j] = f2bf(f0[j]); v[4 + j] = f2bf(f1[j]); }
                        }
                        *(short8*)(sA + ((r * 512 + (q & 1) * 128 + c * 16) ^ ((r & 7) << 4))) = v;
                    }
                }
            } else {
                const float* ar = agg + (size_t)node * HID + (q & 1) * 64;
                #pragma unroll
                for (int c = 0; c < 8; ++c) {
                    short8 v = zer;
                    if (valid) {
                        float4v f0 = *(const float4v*)(ar + c * 8);
                        float4v f1 = *(const float4v*)(ar + c * 8 + 4);
                        #pragma unroll
                        for (int j = 0; j < 4; ++j) { v[j] = f2bf(f0[j]); v[4 + j] = f2bf(f1[j]); }
                    }
                    *(short8*)(sA + ((r * 512 + 256 + (q & 1) * 128 + c * 16) ^ ((r & 7) << 4))) = v;
                }
            }
        }
        __syncthreads();
        f32x16 acc[2] = {};
        int arow = mhalf * 32 + l31;
        const short* bp0 = updwt + (size_t)(nhalf * 64 + l31) * 256 + khalf * 8;
        const short* bp1 = updwt + (size_t)(nhalf * 64 + 32 + l31) * 256 + khalf * 8;
        for (int kk = 0; kk < 16; ++kk) {
            short8 a  = *(short8*)(sA + ((arow * 512 + kk * 32 + khalf * 16) ^ ((arow & 7) << 4)));
            short8 w0 = *(const short8*)(bp0 + kk * 16);
            short8 w1 = *(const short8*)(bp1 + kk * 16);
            acc[0] = __builtin_amdgcn_mfma_f32_32x32x16_bf16(a, w0, acc[0], 0, 0, 0);
            acc[1] = __builtin_amdgcn_mfma_f32_32x32x16_bf16(a, w1, acc[1], 0, 0, 0);
        }
        #pragma unroll
        for (int ni = 0; ni < 2; ++ni) {
            int col = nhalf * 64 + ni * 32 + l31;
            #pragma unroll
            for (int r = 0; r < 16; ++r) {
                int node = tile * 64 + mhalf * 32 + crow(r, khalf);
                if (node < N) {
                    float val = siluf(acc[ni][r] + bv[ni] + h[(size_t)node * HID + col]);
                    h[(size_t)node * HID + col] = val;
                    if (hb) hb[(size_t)node * HID + col] = f2bf(val);
                }
            }
        }
    }
}

// ---------------- MFMA edge-fields kernel ----------------
__global__ __launch_bounds__(256) void fields_mfma_kernel(
    const float* __restrict__ h, const short* __restrict__ hb,
    const int* __restrict__ conn, const float* __restrict__ bc,
    const float* __restrict__ efW1, const float* __restrict__ efb1,
    const float* __restrict__ efb2, const float* __restrict__ efb3,
    const short* __restrict__ efw1t, const short* __restrict__ efw2t, const short* __restrict__ efw3t,
    float* __restrict__ f_out, int EC, int nq, int ntiles)
{
    __shared__ char sA1[64 * 512];
    __shared__ char sA2[64 * 128];
    __shared__ char sF2[64 * 128];
    __shared__ float bcis[64], bcjs[64];
    int tid = threadIdx.x, ln = tid & 63, wave = tid >> 6;
    int mhalf = wave & 1, nhalf = wave >> 1, l31 = ln & 31, khalf = ln >> 5;
    int col = nhalf * 32 + l31;
    float w1x = efW1[col];
    float b1v = efb1[col], b2v = efb2[col];
    float b3v = (l31 < 3) ? efb3[l31] : 0.f;
    float inv = (nq > 1) ? 1.f / (float)(nq - 1) : 0.f;
    short8 zer;
    #pragma unroll
    for (int j = 0; j < 8; ++j) zer[j] = 0;

    #pragma unroll 1
    for (int tile = blockIdx.x; tile < ntiles; tile += gridDim.x) {
        __syncthreads();
        {
            int r = tid >> 2, q = tid & 3;
            long p = (long)tile * 64 + r;
            bool valid = p < EC;
            int node = 0;
            if (valid) node = conn[p * 2 + (q >> 1)];
            if (q == 0) {
                bcis[r] = valid ? bc[conn[p * 2]] : 0.f;
                bcjs[r] = valid ? bc[conn[p * 2 + 1]] : 0.f;
            }
            int cbyte = (q >> 1) * 256 + (q & 1) * 128;
            if (hb) {
                const short8* hr8 = (const short8*)(hb + (size_t)node * HID + (q & 1) * 64);
                #pragma unroll
                for (int c = 0; c < 8; ++c) {
                    short8 v = valid ? hr8[c] : zer;
                    *(short8*)(sA1 + ((r * 512 + cbyte + c * 16) ^ ((r & 7) << 4))) = v;
                }
            } else {
                const float* hr = h + (size_t)node * HID + (q & 1) * 64;
                #pragma unroll
                for (int c = 0; c < 8; ++c) {
                    short8 v = zer;
                    if (valid) {
                        float4v f0 = *(const float4v*)(hr + c * 8);
                        float4v f1 = *(const float4v*)(hr + c * 8 + 4);
                        #pragma unroll
                        for (int j = 0; j < 4; ++j) { v[j] = f2bf(f0[j]); v[4 + j] = f2bf(f1[j]); }
                    }
                    *(short8*)(sA1 + ((r * 512 + cbyte + c * 16) ^ ((r & 7) << 4))) = v;
                }
            }
        }
        __syncthreads();
        f32x16 hp = {};
        int arow = mhalf * 32 + l31;
        for (int kk = 0; kk < 16; ++kk) {
            short8 a = *(short8*)(sA1 + ((arow * 512 + kk * 32 + khalf * 16) ^ ((arow & 7) << 4)));
            short8 b = *(const short8*)(efw1t + (size_t)col * 256 + kk * 16 + khalf * 8);
            hp = __builtin_amdgcn_mfma_f32_32x32x16_bf16(a, b, hp, 0, 0, 0);
        }
        #pragma unroll
        for (int r = 0; r < 16; ++r) hp[r] += b1v;

        for (int q = 0; q < nq; ++q) {
            float xi = (float)q * inv;
            #pragma unroll
            for (int r = 0; r < 16; ++r) {
                float f1 = siluf(fmaf(xi, w1x, hp[r]));
                int row = mhalf * 32 + crow(r, khalf);
                *(short*)(sA2 + ((row * 128 + col * 2) ^ ((row & 7) << 4))) = f2bf(f1);
            }
            __syncthreads();
            f32x16 f2a = {};
            for (int kk = 0; kk < 4; ++kk) {
                short8 a = *(short8*)(sA2 + ((arow * 128 + kk * 32 + khalf * 16) ^ ((l31 & 7) << 4)));
                short8 b = *(const short8*)(efw2t + (size_t)col * 64 + kk * 16 + khalf * 8);
                f2a = __builtin_amdgcn_mfma_f32_32x32x16_bf16(a, b, f2a, 0, 0, 0);
            }
            #pragma unroll
            for (int r = 0; r < 16; ++r) {
                float f2 = siluf(f2a[r] + b2v);
                int row = mhalf * 32 + crow(r, khalf);
                *(short*)(sF2 + ((row * 128 + col * 2) ^ ((row & 7) << 4))) = f2bf(f2);
            }
            __syncthreads();
            f32x16 oa = {};
            for (int kk = 0; kk < 4; ++kk) {
                short8 a = *(short8*)(sF2 + ((arow * 128 + kk * 32 + khalf * 16) ^ ((l31 & 7) << 4)));
                short8 b = *(const short8*)(efw3t + (size_t)l31 * 64 + kk * 16 + khalf * 8);
                oa = __builtin_amdgcn_mfma_f32_32x32x16_bf16(a, b, oa, 0, 0, 0);
            }
            if (nhalf == 0 && l31 < 3) {
                #pragma unroll
                for (int r = 0; r < 16; ++r) {
                    int row = mhalf * 32 + crow(r, khalf);
                    long p = (long)tile * 64 + row;
                    if (p < EC) {
                        float mask = (1.f - bcis[row] * (1.f - xi)) * (1.f - bcjs[row] * xi);
                        f_out[((size_t)p * nq + q) * 3 + l31] = (oa[r] + b3v) * mask;
                    }
                }
            }
        }
    }
}

// ---------------- aux: prop passthrough + xi fill ----------------
__global__ void aux_kernel(const float* __restrict__ prop, float* __restrict__ out_p,
                           float* __restrict__ out_xi, int EC, int nq, float inv)
{
    int i = blockIdx.x * blockDim.x + threadIdx.x;
    if (i < EC) out_p[i] = prop[i];
    if (i < EC * nq) out_xi[i] = (float)(i % nq) * inv;
}

extern "C" void kernel_launch(void* const* d_in, const int* in_sizes, int n_in,
                              void* d_out, int out_size, void* d_ws, size_t ws_size,
                              hipStream_t stream) {
    const float* x     = (const float*)d_in[0];
    const int*   ei    = (const int*)d_in[1];
    const float* ea    = (const float*)d_in[2];
    const int*   conn  = (const int*)d_in[3];
    const float* bc    = (const float*)d_in[4];
    const float* prop  = (const float*)d_in[5];
    const float* encW1 = (const float*)d_in[7];
    const float* encb1 = (const float*)d_in[8];
    const float* encW2 = (const float*)d_in[9];
    const float* encb2 = (const float*)d_in[10];
    const float* msgW1 = (const float*)d_in[11];
    const float* msgb1 = (const float*)d_in[12];
    const float* msgW2 = (const float*)d_in[13];
    const float* msgb2 = (const float*)d_in[14];
    const float* updW  = (const float*)d_in[15];
    const float* updb  = (const float*)d_in[16];
    const float* efW1  = (const float*)d_in[17];
    const float* efb1  = (const float*)d_in[18];
    const float* efW2  = (const float*)d_in[19];
    const float* efb2  = (const float*)d_in[20];
    const float* efW3  = (const float*)d_in[21];
    const float* efb3  = (const float*)d_in[22];

    int N  = in_sizes[0] / 9;
    int E  = in_sizes[1] / 2;
    int EC = in_sizes[5];
    int nl = in_sizes[11] / (MSG_IN * HID);
    int nq = (int)(((long long)out_size - (long long)N * HID - EC) / (4LL * EC));

    float* out    = (float*)d_out;
    float* h      = out;
    float* out_xi = out + (size_t)N * HID;
    float* out_f  = out_xi + (size_t)EC * nq;
    float* out_p  = out_f + (size_t)EC * nq * 3;

    // ws: [weights][hb][agg][icnt N][icur N][btot 1024][eord E][srcs_s E][dsts_s E][ea_s 16E]
    size_t w1t_e = (size_t)nl * 128 * KCAP;
    size_t w2t_e = (size_t)nl * 128 * HID;
    size_t updwt_e = (size_t)nl * 128 * 256;
    size_t efw1t_e = 64 * 256, efw2t_e = 64 * 64, efw3t_e = 32 * 64;
    short* w1t   = (short*)d_ws;
    short* w2t   = w1t + w1t_e;
    short* updwt = w2t + w2t_e;
    short* efw1t = updwt + updwt_e;
    short* efw2t = efw1t + efw1t_e;
    short* efw3t = efw2t + efw2t_e;
    size_t wbytes = (w1t_e + w2t_e + updwt_e + efw1t_e + efw2t_e + efw3t_e) * 2;
    wbytes = (wbytes + 255) & ~(size_t)255;
    size_t hb_bytes  = (size_t)N * HID * 2;
    size_t agg_bytes = (size_t)N * HID * 4;
    size_t sort_bytes = ((size_t)2 * N + 1024 + (size_t)3 * E) * 4 + (size_t)E * 32;

    short* hb = nullptr;
    float* agg;
    int *icnt = nullptr, *icur = nullptr, *btot = nullptr, *eord = nullptr;
    int *srcs_s = nullptr, *dsts_s = nullptr;
    short* ea_s = nullptr;
    if (ws_size >= wbytes + hb_bytes + agg_bytes + sort_bytes) {
        char* p = (char*)d_ws + wbytes;
        hb = (short*)p;      p += hb_bytes;
        agg = (float*)p;     p += agg_bytes;
        icnt = (int*)p;      p += (size_t)N * 4;
        icur = (int*)p;      p += (size_t)N * 4;
        btot = (int*)p;      p += 1024 * 4;
        eord = (int*)p;      p += (size_t)E * 4;
        srcs_s = (int*)p;    p += (size_t)E * 4;
        dsts_s = (int*)p;    p += (size_t)E * 4;
        ea_s = (short*)p;
    } else if (ws_size >= wbytes + hb_bytes + agg_bytes) {
        hb  = (short*)((char*)d_ws + wbytes);
        agg = (float*)((char*)d_ws + wbytes + hb_bytes);
    } else {
        agg = (float*)((char*)d_ws + wbytes);
    }

    hipFuncSetAttribute((const void*)msg_mfma_kernel,
                        hipFuncAttributeMaxDynamicSharedMemorySize, MSG_LDS);

    encoder_kernel<<<N, 128, 0, stream>>>(x, encW1, encb1, encW2, encb2, h, hb);

    {
        int chunks = nl * 128 * (KCAP / 8) + nl * 128 * (HID / 8) + nl * 128 * 32
                   + 64 * 32 + 64 * 8 + 32 * 8;
        convert_w_kernel<<<(chunks + 255) / 256, 256, 0, stream>>>(
            msgW1, msgW2, updW, efW1, efW2, efW3,
            w1t, w2t, updwt, efw1t, efw2t, efw3t, nl);
    }

    if (ea_s) {
        int nb = (N + 255) / 256;
        hipMemsetAsync(icnt, 0, (size_t)N * 4, stream);
        hist_kernel<<<512, 256, 0, stream>>>(ei, icnt, E);
        scanA_kernel<<<nb, 256, 0, stream>>>(icnt, btot, N);
        scanB_kernel<<<1, 1024, 0, stream>>>(btot, nb);
        scanC_kernel<<<nb, 256, 0, stream>>>(icnt, btot, icur, N);
        scatter_kernel<<<512, 256, 0, stream>>>(ei, icur, eord, E);
        reorder_kernel<<<512, 256, 0, stream>>>(ei, ea, eord, srcs_s, dsts_s, ea_s, E);
    }

    int ntiles = (E + TILE_E - 1) / TILE_E;
    int utiles = (N + 63) / 64;
    for (int l = 0; l < nl; ++l) {
        hipMemsetAsync(agg, 0, agg_bytes, stream);
        msg_mfma_kernel<<<256, 512, MSG_LDS, stream>>>(
            h, hb, ei, ea, srcs_s, dsts_s, ea_s,
            w1t + (size_t)l * 128 * KCAP, msgb1 + (size_t)l * HID,
            w2t + (size_t)l * 128 * HID,  msgb2 + (size_t)l * HID,
            agg, E, ntiles);
        upd_mfma_kernel<<<512, 256, 0, stream>>>(
            h, hb, agg, updwt + (size_t)l * 128 * 256, updb + (size_t)l * HID, N, utiles);
    }

    int ftiles = (EC + 63) / 64;
    fields_mfma_kernel<<<512, 256, 0, stream>>>(
        h, hb, conn, bc, efW1, efb1, efb2, efb3, efw1t, efw2t, efw3t,
        out_f, EC, nq, ftiles);

    float inv = (nq > 1) ? 1.f / (float)(nq - 1) : 0.f;
    aux_kernel<<<(EC * nq + 255) / 256, 256, 0, stream>>>(prop, out_p, out_xi, EC, nq, inv);
}

// Round 14
// 1748.582 us; speedup vs baseline: 1.6744x; 1.0032x over previous
//
#include <hip/hip_runtime.h>
#include <hip/hip_bf16.h>

#define HID 128
#define EA_DIM 11
#define MSG_IN (2 * HID + EA_DIM)   // 267
#define TILE_E 128
#define KCAP 272                     // layer-1 K padded to 17*16
#define KB (KCAP * 2)                // 544 bytes per LDS row
#define MSG_LDS 139264               // W1T (69632) + A1/A2 union (69632)

typedef __attribute__((ext_vector_type(8))) short short8;
typedef __attribute__((ext_vector_type(16))) float f32x16;
typedef __attribute__((ext_vector_type(4))) float float4v;

__device__ __forceinline__ float siluf(float x) { return x / (1.f + __expf(-x)); }
__device__ __forceinline__ short f2bf(float f) {
    __hip_bfloat16 h = __float2bfloat16(f);
    return *reinterpret_cast<short*>(&h);
}
__device__ __forceinline__ int crow(int r, int khalf) { return (r & 3) + 8 * (r >> 2) + 4 * khalf; }

// Bijective linear-address swizzle (R13-verified)
__device__ __forceinline__ int swz(int a) { return a ^ (((a >> 7) & 7) << 4); }

// ---------------- encoder ----------------
__global__ __launch_bounds__(128) void encoder_kernel(
    const float* __restrict__ x, const float* __restrict__ W1, const float* __restrict__ b1,
    const float* __restrict__ W2, const float* __restrict__ b2,
    float* __restrict__ h, short* __restrict__ hb)
{
    int i = blockIdx.x, j = threadIdx.x;
    __shared__ float xs[9];
    __shared__ float t1[HID];
    if (j < 9) xs[j] = x[(size_t)i * 9 + j];
    __syncthreads();
    float acc = b1[j];
    #pragma unroll
    for (int k = 0; k < 9; ++k) acc = fmaf(xs[k], W1[k * HID + j], acc);
    t1[j] = siluf(acc);
    __syncthreads();
    float acc2 = b2[j];
    #pragma unroll 8
    for (int k = 0; k < HID; ++k) acc2 = fmaf(t1[k], W2[k * HID + j], acc2);
    float v = siluf(acc2);
    h[(size_t)i * HID + j] = v;
    if (hb) hb[(size_t)i * HID + j] = f2bf(v);
}

// ---- one-time weight conversion to transposed bf16 layouts ----
__global__ void convert_w_kernel(
    const float* __restrict__ msgW1, const float* __restrict__ msgW2,
    const float* __restrict__ updW,
    const float* __restrict__ efW1, const float* __restrict__ efW2, const float* __restrict__ efW3,
    short* __restrict__ w1t, short* __restrict__ w2t, short* __restrict__ updwt,
    short* __restrict__ efw1t, short* __restrict__ efw2t, short* __restrict__ efw3t, int nl)
{
    int gid = blockIdx.x * blockDim.x + threadIdx.x;
    int n1 = nl * 128 * (KCAP / 8);
    int n2 = nl * 128 * (HID / 8);
    int n3 = nl * 128 * 32;
    int n4 = 64 * 32, n5 = 64 * 8, n6 = 32 * 8;
    short8 v;
    if (gid < n1) {
        int c = gid % (KCAP / 8);
        int rem = gid / (KCAP / 8);
        int n = rem % 128, lay = rem / 128;
        #pragma unroll
        for (int j = 0; j < 8; ++j) {
            int k = c * 8 + j;
            v[j] = (k < MSG_IN) ? f2bf(msgW1[(size_t)lay * MSG_IN * HID + (size_t)k * HID + n]) : (short)0;
        }
        *(short8*)(w1t + ((size_t)lay * 128 + n) * KCAP + c * 8) = v;
    } else if (gid < n1 + n2) {
        int g = gid - n1;
        int c = g % (HID / 8);
        int rem = g / (HID / 8);
        int n = rem % 128, lay = rem / 128;
        #pragma unroll
        for (int j = 0; j < 8; ++j)
            v[j] = f2bf(msgW2[(size_t)lay * HID * HID + (size_t)(c * 8 + j) * HID + n]);
        *(short8*)(w2t + ((size_t)lay * 128 + n) * HID + c * 8) = v;
    } else if (gid < n1 + n2 + n3) {
        int g = gid - n1 - n2;
        int c = g & 31;
        int rem = g >> 5;
        int n = rem & 127, lay = rem >> 7;
        #pragma unroll
        for (int j = 0; j < 8; ++j)
            v[j] = f2bf(updW[(size_t)lay * 256 * 128 + (size_t)(c * 8 + j) * 128 + n]);
        *(short8*)(updwt + ((size_t)lay * 128 + n) * 256 + c * 8) = v;
    } else if (gid < n1 + n2 + n3 + n4) {
        int g = gid - n1 - n2 - n3;
        int c = g & 31, n = g >> 5;
        #pragma unroll
        for (int j = 0; j < 8; ++j)
            v[j] = f2bf(efW1[(size_t)(c * 8 + j + 1) * 64 + n]);
        *(short8*)(efw1t + (size_t)n * 256 + c * 8) = v;
    } else if (gid < n1 + n2 + n3 + n4 + n5) {
        int g = gid - n1 - n2 - n3 - n4;
        int c = g & 7, n = g >> 3;
        #pragma unroll
        for (int j = 0; j < 8; ++j)
            v[j] = f2bf(efW2[(size_t)(c * 8 + j) * 64 + n]);
        *(short8*)(efw2t + (size_t)n * 64 + c * 8) = v;
    } else if (gid < n1 + n2 + n3 + n4 + n5 + n6) {
        int g = gid - n1 - n2 - n3 - n4 - n5;
        int c = g & 7, n = g >> 3;
        #pragma unroll
        for (int j = 0; j < 8; ++j)
            v[j] = (n < 3) ? f2bf(efW3[(size_t)(c * 8 + j) * 3 + n]) : (short)0;
        *(short8*)(efw3t + (size_t)n * 64 + c * 8) = v;
    }
}

// ---------------- CSR sort preprocessing ----------------
__global__ void hist_kernel(const int* __restrict__ ei, int* __restrict__ cnt, int E)
{
    for (int e = blockIdx.x * blockDim.x + threadIdx.x; e < E; e += gridDim.x * blockDim.x)
        atomicAdd(&cnt[ei[(size_t)E + e]], 1);
}
__global__ __launch_bounds__(256) void scanA_kernel(const int* __restrict__ cnt, int* __restrict__ btot, int N)
{
    __shared__ int s[256];
    int i = blockIdx.x * 256 + threadIdx.x;
    s[threadIdx.x] = (i < N) ? cnt[i] : 0;
    __syncthreads();
    for (int o = 128; o > 0; o >>= 1) {
        if (threadIdx.x < o) s[threadIdx.x] += s[threadIdx.x + o];
        __syncthreads();
    }
    if (threadIdx.x == 0) btot[blockIdx.x] = s[0];
}
__global__ __launch_bounds__(1024) void scanB_kernel(int* __restrict__ btot, int nb)
{
    __shared__ int s[1024];
    int t = threadIdx.x;
    int v = (t < nb) ? btot[t] : 0;
    s[t] = v;
    __syncthreads();
    for (int o = 1; o < 1024; o <<= 1) {
        int tv = 0;
        if (t >= o) tv = s[t - o];
        __syncthreads();
        s[t] += tv;
        __syncthreads();
    }
    if (t < nb) btot[t] = s[t] - v;   // exclusive
}
__global__ __launch_bounds__(256) void scanC_kernel(const int* __restrict__ cnt, const int* __restrict__ btot,
                                                    int* __restrict__ cur, int N)
{
    __shared__ int s[256];
    int i = blockIdx.x * 256 + threadIdx.x;
    int t = threadIdx.x;
    int v = (i < N) ? cnt[i] : 0;
    s[t] = v;
    __syncthreads();
    for (int o = 1; o < 256; o <<= 1) {
        int tv = 0;
        if (t >= o) tv = s[t - o];
        __syncthreads();
        s[t] += tv;
        __syncthreads();
    }
    if (i < N) cur[i] = btot[blockIdx.x] + s[t] - v;   // exclusive start
}
__global__ void scatter_kernel(const int* __restrict__ ei, int* __restrict__ cur,
                               int* __restrict__ eord, int E)
{
    for (int e = blockIdx.x * blockDim.x + threadIdx.x; e < E; e += gridDim.x * blockDim.x) {
        int d = ei[(size_t)E + e];
        int p = atomicAdd(&cur[d], 1);
        eord[p] = e;
    }
}
__global__ void reorder_kernel(const int* __restrict__ ei, const float* __restrict__ ea,
                               const int* __restrict__ eord,
                               int* __restrict__ srcs_s, int* __restrict__ dsts_s,
                               short* __restrict__ ea_s, int E)
{
    for (int p = blockIdx.x * blockDim.x + threadIdx.x; p < E; p += gridDim.x * blockDim.x) {
        int es = eord[p];
        srcs_s[p] = ei[es];
        dsts_s[p] = ei[(size_t)E + es];
        short tv[16];
        #pragma unroll
        for (int j = 0; j < 16; ++j) tv[j] = 0;
        #pragma unroll
        for (int j = 0; j < EA_DIM; ++j) tv[j] = f2bf(ea[(size_t)es * EA_DIM + j]);
        short8 v0, v1;
        #pragma unroll
        for (int j = 0; j < 8; ++j) { v0[j] = tv[j]; v1[j] = tv[8 + j]; }
        *(short8*)(ea_s + (size_t)p * 16) = v0;
        *(short8*)(ea_s + (size_t)p * 16 + 8) = v1;
    }
}

// ======== MFMA message kernel: R13 base; NEW: in-register run-length dedup
// ======== replaces the m-store + LDS segreduce (6 -> 4 barriers per tile).
// ======== Rows within a lane are ascending and dsts[] is sorted, so each lane
// ======== run-accumulates its 32 acc2 values and flushes one atomic per run.
__global__ __launch_bounds__(512, 1) void msg_mfma_kernel(
    const float* __restrict__ h, const short* __restrict__ hb,
    const int* __restrict__ ei, const float* __restrict__ ea,
    const int* __restrict__ srcs_s, const int* __restrict__ dsts_s, const short* __restrict__ ea_s,
    const short* __restrict__ w1t, const float* __restrict__ b1,
    const short* __restrict__ w2t, const float* __restrict__ b2,
    float* __restrict__ agg, int E, int ntiles)
{
    extern __shared__ char smem[];       // [W1T 69632 | A1/A2 union 69632]
    char* sA = smem + 69632;
    __shared__ int dsts[TILE_E];

    int tid = threadIdx.x, ln = tid & 63, wave = tid >> 6;
    int mh = wave & 1, nq4 = wave >> 1;        // 2 (M) x 4 (N) waves
    int l31 = ln & 31, khalf = ln >> 5;

    // ---- stage W1T once per block (address-swizzled) ----
    {
        int row = tid & 127, grp = tid >> 7;
        for (int c = grp; c < 34; c += 4) {
            short8 v = *(const short8*)(w1t + (size_t)row * KCAP + c * 8);
            *(short8*)(smem + swz(row * KB + c * 16)) = v;
        }
    }

    int col = nq4 * 32 + l31;                  // this wave's output column
    float b1v = b1[col], b2v = b2[col];
    short8 zer;
    #pragma unroll
    for (int j = 0; j < 8; ++j) zer[j] = 0;
    int ar0 = mh * 64 + l31;                   // A rows (and +32)
    const short8* w2r = (const short8*)(w2t + (size_t)col * HID);

    bool sorted = (ea_s != nullptr) && (hb != nullptr);

    // ---- prefetch state (sorted path): 4 threads per edge row ----
    int pr = tid >> 2, pq = tid & 3;
    int pf_idx = 0; bool pf_valid = false;
    short8 pf_h[8];
    short8 pf_e0 = zer, pf_e1 = zer;

    if (sorted) {
        long ep = (long)blockIdx.x * TILE_E + pr;
        pf_valid = ep < E;
        pf_idx = pf_valid ? ((pq < 2) ? srcs_s[ep] : dsts_s[ep]) : 0;
        const short8* hr8 = (const short8*)(hb + (size_t)pf_idx * HID + (pq & 1) * 64);
        #pragma unroll
        for (int c = 0; c < 8; ++c) pf_h[c] = hr8[c];
        if (pq == 3 && pf_valid) {
            pf_e0 = *(const short8*)(ea_s + (size_t)ep * 16);
            pf_e1 = *(const short8*)(ea_s + (size_t)ep * 16 + 8);
        }
    }

    #pragma unroll 1
    for (int tile = blockIdx.x; tile < ntiles; tile += gridDim.x) {
        __syncthreads();   // b0: prior-iter A2/dsts reads done (covers W1T staging iter 0)

        if (sorted) {
            // ---- write prefetched tile -> LDS ----
            int dbase = (pq >> 1) * 256 + (pq & 1) * 128;
            #pragma unroll
            for (int c = 0; c < 8; ++c) {
                short8 v = pf_valid ? pf_h[c] : zer;
                *(short8*)(sA + swz(pr * KB + dbase + c * 16)) = v;
            }
            if (pq == 2) dsts[pr] = pf_valid ? pf_idx : -1;
            if (pq == 3) {
                *(short8*)(sA + swz(pr * KB + 512)) = pf_valid ? pf_e0 : zer;
                *(short8*)(sA + swz(pr * KB + 528)) = pf_valid ? pf_e1 : zer;
            }
        } else {
            int r = pr, q = pq;
            long ep = (long)tile * TILE_E + r;
            bool valid = ep < E;
            int idx = 0;
            if (valid) idx = (q < 2) ? ei[ep] : ei[(size_t)E + ep];
            int half = q & 1;
            int dbase = (q >> 1) * 256 + half * 128;
            if (hb) {
                const short8* hr8 = (const short8*)(hb + (size_t)idx * HID + half * 64);
                #pragma unroll
                for (int c = 0; c < 8; ++c) {
                    short8 v = valid ? hr8[c] : zer;
                    *(short8*)(sA + swz(r * KB + dbase + c * 16)) = v;
                }
            } else {
                const float* hr = h + (size_t)idx * HID + half * 64;
                #pragma unroll
                for (int c = 0; c < 8; ++c) {
                    short8 v = zer;
                    if (valid) {
                        float4v f0 = *(const float4v*)(hr + c * 8);
                        float4v f1 = *(const float4v*)(hr + c * 8 + 4);
                        #pragma unroll
                        for (int j = 0; j < 4; ++j) { v[j] = f2bf(f0[j]); v[4 + j] = f2bf(f1[j]); }
                    }
                    *(short8*)(sA + swz(r * KB + dbase + c * 16)) = v;
                }
            }
            if (q == 2) dsts[r] = valid ? idx : -1;
            if (q == 3) {
                short8 v0 = zer, v1 = zer;
                if (valid) {
                    short tv[16];
                    #pragma unroll
                    for (int j = 0; j < 16; ++j) tv[j] = 0;
                    #pragma unroll
                    for (int j = 0; j < EA_DIM; ++j) tv[j] = f2bf(ea[(size_t)ep * EA_DIM + j]);
                    #pragma unroll
                    for (int j = 0; j < 8; ++j) { v0[j] = tv[j]; v1[j] = tv[8 + j]; }
                }
                *(short8*)(sA + swz(r * KB + 512)) = v0;
                *(short8*)(sA + swz(r * KB + 528)) = v1;
            }
        }
        __syncthreads();   // b1: A1 staged

        if (sorted) {
            // ---- issue NEXT tile's gather (latency hides under MFMA phases) ----
            long ep = (long)(tile + gridDim.x) * TILE_E + pr;
            pf_valid = ep < E;
            pf_idx = pf_valid ? ((pq < 2) ? srcs_s[ep] : dsts_s[ep]) : 0;
            const short8* hr8 = (const short8*)(hb + (size_t)pf_idx * HID + (pq & 1) * 64);
            #pragma unroll
            for (int c = 0; c < 8; ++c) pf_h[c] = hr8[c];
            if (pq == 3 && pf_valid) {
                pf_e0 = *(const short8*)(ea_s + (size_t)ep * 16);
                pf_e1 = *(const short8*)(ea_s + (size_t)ep * 16 + 8);
            }
        }

        // ---- layer 1: wave computes 64 rows x 32 cols; B from LDS W1T ----
        f32x16 acc1[2] = {};
        for (int kk = 0; kk < 17; ++kk) {
            int kb = kk * 32 + khalf * 16;
            short8 a0 = *(short8*)(sA + swz(ar0 * KB + kb));
            short8 a1 = *(short8*)(sA + swz((ar0 + 32) * KB + kb));
            short8 w  = *(short8*)(smem + swz(col * KB + kb));
            acc1[0] = __builtin_amdgcn_mfma_f32_32x32x16_bf16(a0, w, acc1[0], 0, 0, 0);
            acc1[1] = __builtin_amdgcn_mfma_f32_32x32x16_bf16(a1, w, acc1[1], 0, 0, 0);
        }
        __syncthreads();   // b2: A1 reads done before A2 overwrite

        // ---- bias + silu -> A2 (bf16, 256B stride, row swizzle) ----
        #pragma unroll
        for (int mi = 0; mi < 2; ++mi)
            #pragma unroll
            for (int r = 0; r < 16; ++r) {
                float s = siluf(acc1[mi][r] + b1v);
                int row = mh * 64 + mi * 32 + crow(r, khalf);
                *(short*)(sA + ((row * 256 + col * 2) ^ ((row & 7) << 4))) = f2bf(s);
            }
        __syncthreads();   // b3: A2 visible

        // ---- layer 2: B from global w2t (L1-resident, 32 KB) ----
        f32x16 acc2[2];
        #pragma unroll
        for (int mi = 0; mi < 2; ++mi)
            #pragma unroll
            for (int r = 0; r < 16; ++r) acc2[mi][r] = b2v;
        for (int kk = 0; kk < 8; ++kk) {
            int kb = kk * 32 + khalf * 16;
            short8 a0 = *(short8*)(sA + ((ar0 * 256 + kb) ^ ((ar0 & 7) << 4)));
            short8 a1 = *(short8*)(sA + (((ar0 + 32) * 256 + kb) ^ (((ar0 + 32) & 7) << 4)));
            short8 w  = w2r[kk * 2 + khalf];
            acc2[0] = __builtin_amdgcn_mfma_f32_32x32x16_bf16(a0, w, acc2[0], 0, 0, 0);
            acc2[1] = __builtin_amdgcn_mfma_f32_32x32x16_bf16(a1, w, acc2[1], 0, 0, 0);
        }

        if (sorted) {
            // ---- in-register run-length dedup + atomic flush ----
            // rows ascending per lane; dsts sorted => runs are contiguous
            float s = 0.f; int dprev = -1;
            #pragma unroll
            for (int mi = 0; mi < 2; ++mi)
                #pragma unroll
                for (int r = 0; r < 16; ++r) {
                    int row = mh * 64 + mi * 32 + crow(r, khalf);
                    int d = dsts[row];
                    if (d != dprev) {
                        if (dprev >= 0) atomicAdd(agg + (size_t)dprev * HID + col, s);
                        s = 0.f; dprev = d;
                    }
                    if (d >= 0) s += acc2[mi][r];
                }
            if (dprev >= 0) atomicAdd(agg + (size_t)dprev * HID + col, s);
        } else {
            // ---- fallback: direct atomic scatter ----
            #pragma unroll
            for (int mi = 0; mi < 2; ++mi)
                #pragma unroll
                for (int r = 0; r < 16; ++r) {
                    int row = mh * 64 + mi * 32 + crow(r, khalf);
                    int d = dsts[row];
                    if (d >= 0) atomicAdd(agg + (size_t)d * HID + col, acc2[mi][r]);
                }
        }
    }
}

// ---------------- MFMA update kernel ----------------
__global__ __launch_bounds__(256) void upd_mfma_kernel(
    float* __restrict__ h, short* __restrict__ hb, const float* __restrict__ agg,
    const short* __restrict__ updwt, const float* __restrict__ b, int N, int ntiles)
{
    __shared__ char sA[64 * 512];
    int tid = threadIdx.x, ln = tid & 63, wave = tid >> 6;
    int mhalf = wave & 1, nhalf = wave >> 1, l31 = ln & 31, khalf = ln >> 5;
    float bv[2];
    #pragma unroll
    for (int ni = 0; ni < 2; ++ni) bv[ni] = b[nhalf * 64 + ni * 32 + l31];
    short8 zer;
    #pragma unroll
    for (int j = 0; j < 8; ++j) zer[j] = 0;

    #pragma unroll 1
    for (int tile = blockIdx.x; tile < ntiles; tile += gridDim.x) {
        __syncthreads();
        {
            int r = tid >> 2, q = tid & 3;
            int node = tile * 64 + r;
            bool valid = node < N;
            if (q < 2) {
                if (hb) {
                    const short8* hr8 = (const short8*)(hb + (size_t)node * HID + (q & 1) * 64);
                    #pragma unroll
                    for (int c = 0; c < 8; ++c) {
                        short8 v = valid ? hr8[c] : zer;
                        *(short8*)(sA + ((r * 512 + (q & 1) * 128 + c * 16) ^ ((r & 7) << 4))) = v;
                    }
                } else {
                    const float* hr = h + (size_t)node * HID + (q & 1) * 64;
                    #pragma unroll
                    for (int c = 0; c < 8; ++c) {
                        short8 v = zer;
                        if (valid) {
                            float4v f0 = *(const float4v*)(hr + c * 8);
                            float4v f1 = *(const float4v*)(hr + c * 8 + 4);
                            #pragma unroll
                            for (int j = 0; j < 4; ++j) { v[j] = f2bf(f0[j]); v[4 + j] = f2bf(f1[j]); }
                        }
                        *(short8*)(sA + ((r * 512 + (q & 1) * 128 + c * 16) ^ ((r & 7) << 4))) = v;
                    }
                }
            } else {
                const float* ar = agg + (size_t)node * HID + (q & 1) * 64;
                #pragma unroll
                for (int c = 0; c < 8; ++c) {
                    short8 v = zer;
                    if (valid) {
                        float4v f0 = *(const float4v*)(ar + c * 8);
                        float4v f1 = *(const float4v*)(ar + c * 8 + 4);
                        #pragma unroll
                        for (int j = 0; j < 4; ++j) { v[j] = f2bf(f0[j]); v[4 + j] = f2bf(f1[j]); }
                    }
                    *(short8*)(sA + ((r * 512 + 256 + (q & 1) * 128 + c * 16) ^ ((r & 7) << 4))) = v;
                }
            }
        }
        __syncthreads();
        f32x16 acc[2] = {};
        int arow = mhalf * 32 + l31;
        const short* bp0 = updwt + (size_t)(nhalf * 64 + l31) * 256 + khalf * 8;
        const short* bp1 = updwt + (size_t)(nhalf * 64 + 32 + l31) * 256 + khalf * 8;
        for (int kk = 0; kk < 16; ++kk) {
            short8 a  = *(short8*)(sA + ((arow * 512 + kk * 32 + khalf * 16) ^ ((arow & 7) << 4)));
            short8 w0 = *(const short8*)(bp0 + kk * 16);
            short8 w1 = *(const short8*)(bp1 + kk * 16);
            acc[0] = __builtin_amdgcn_mfma_f32_32x32x16_bf16(a, w0, acc[0], 0, 0, 0);
            acc[1] = __builtin_amdgcn_mfma_f32_32x32x16_bf16(a, w1, acc[1], 0, 0, 0);
        }
        #pragma unroll
        for (int ni = 0; ni < 2; ++ni) {
            int col = nhalf * 64 + ni * 32 + l31;
            #pragma unroll
            for (int r = 0; r < 16; ++r) {
                int node = tile * 64 + mhalf * 32 + crow(r, khalf);
                if (node < N) {
                    float val = siluf(acc[ni][r] + bv[ni] + h[(size_t)node * HID + col]);
                    h[(size_t)node * HID + col] = val;
                    if (hb) hb[(size_t)node * HID + col] = f2bf(val);
                }
            }
        }
    }
}

// ---------------- MFMA edge-fields kernel ----------------
__global__ __launch_bounds__(256) void fields_mfma_kernel(
    const float* __restrict__ h, const short* __restrict__ hb,
    const int* __restrict__ conn, const float* __restrict__ bc,
    const float* __restrict__ efW1, const float* __restrict__ efb1,
    const float* __restrict__ efb2, const float* __restrict__ efb3,
    const short* __restrict__ efw1t, const short* __restrict__ efw2t, const short* __restrict__ efw3t,
    float* __restrict__ f_out, int EC, int nq, int ntiles)
{
    __shared__ char sA1[64 * 512];
    __shared__ char sA2[64 * 128];
    __shared__ char sF2[64 * 128];
    __shared__ float bcis[64], bcjs[64];
    int tid = threadIdx.x, ln = tid & 63, wave = tid >> 6;
    int mhalf = wave & 1, nhalf = wave >> 1, l31 = ln & 31, khalf = ln >> 5;
    int col = nhalf * 32 + l31;
    float w1x = efW1[col];
    float b1v = efb1[col], b2v = efb2[col];
    float b3v = (l31 < 3) ? efb3[l31] : 0.f;
    float inv = (nq > 1) ? 1.f / (float)(nq - 1) : 0.f;
    short8 zer;
    #pragma unroll
    for (int j = 0; j < 8; ++j) zer[j] = 0;

    #pragma unroll 1
    for (int tile = blockIdx.x; tile < ntiles; tile += gridDim.x) {
        __syncthreads();
        {
            int r = tid >> 2, q = tid & 3;
            long p = (long)tile * 64 + r;
            bool valid = p < EC;
            int node = 0;
            if (valid) node = conn[p * 2 + (q >> 1)];
            if (q == 0) {
                bcis[r] = valid ? bc[conn[p * 2]] : 0.f;
                bcjs[r] = valid ? bc[conn[p * 2 + 1]] : 0.f;
            }
            int cbyte = (q >> 1) * 256 + (q & 1) * 128;
            if (hb) {
                const short8* hr8 = (const short8*)(hb + (size_t)node * HID + (q & 1) * 64);
                #pragma unroll
                for (int c = 0; c < 8; ++c) {
                    short8 v = valid ? hr8[c] : zer;
                    *(short8*)(sA1 + ((r * 512 + cbyte + c * 16) ^ ((r & 7) << 4))) = v;
                }
            } else {
                const float* hr = h + (size_t)node * HID + (q & 1) * 64;
                #pragma unroll
                for (int c = 0; c < 8; ++c) {
                    short8 v = zer;
                    if (valid) {
                        float4v f0 = *(const float4v*)(hr + c * 8);
                        float4v f1 = *(const float4v*)(hr + c * 8 + 4);
                        #pragma unroll
                        for (int j = 0; j < 4; ++j) { v[j] = f2bf(f0[j]); v[4 + j] = f2bf(f1[j]); }
                    }
                    *(short8*)(sA1 + ((r * 512 + cbyte + c * 16) ^ ((r & 7) << 4))) = v;
                }
            }
        }
        __syncthreads();
        f32x16 hp = {};
        int arow = mhalf * 32 + l31;
        for (int kk = 0; kk < 16; ++kk) {
            short8 a = *(short8*)(sA1 + ((arow * 512 + kk * 32 + khalf * 16) ^ ((arow & 7) << 4)));
            short8 b = *(const short8*)(efw1t + (size_t)col * 256 + kk * 16 + khalf * 8);
            hp = __builtin_amdgcn_mfma_f32_32x32x16_bf16(a, b, hp, 0, 0, 0);
        }
        #pragma unroll
        for (int r = 0; r < 16; ++r) hp[r] += b1v;

        for (int q = 0; q < nq; ++q) {
            float xi = (float)q * inv;
            #pragma unroll
            for (int r = 0; r < 16; ++r) {
                float f1 = siluf(fmaf(xi, w1x, hp[r]));
                int row = mhalf * 32 + crow(r, khalf);
                *(short*)(sA2 + ((row * 128 + col * 2) ^ ((row & 7) << 4))) = f2bf(f1);
            }
            __syncthreads();
            f32x16 f2a = {};
            for (int kk = 0; kk < 4; ++kk) {
                short8 a = *(short8*)(sA2 + ((arow * 128 + kk * 32 + khalf * 16) ^ ((l31 & 7) << 4)));
                short8 b = *(const short8*)(efw2t + (size_t)col * 64 + kk * 16 + khalf * 8);
                f2a = __builtin_amdgcn_mfma_f32_32x32x16_bf16(a, b, f2a, 0, 0, 0);
            }
            #pragma unroll
            for (int r = 0; r < 16; ++r) {
                float f2 = siluf(f2a[r] + b2v);
                int row = mhalf * 32 + crow(r, khalf);
                *(short*)(sF2 + ((row * 128 + col * 2) ^ ((row & 7) << 4))) = f2bf(f2);
            }
            __syncthreads();
            f32x16 oa = {};
            for (int kk = 0; kk < 4; ++kk) {
                short8 a = *(short8*)(sF2 + ((arow * 128 + kk * 32 + khalf * 16) ^ ((l31 & 7) << 4)));
                short8 b = *(const short8*)(efw3t + (size_t)l31 * 64 + kk * 16 + khalf * 8);
                oa = __builtin_amdgcn_mfma_f32_32x32x16_bf16(a, b, oa, 0, 0, 0);
            }
            if (nhalf == 0 && l31 < 3) {
                #pragma unroll
                for (int r = 0; r < 16; ++r) {
                    int row = mhalf * 32 + crow(r, khalf);
                    long p = (long)tile * 64 + row;
                    if (p < EC) {
                        float mask = (1.f - bcis[row] * (1.f - xi)) * (1.f - bcjs[row] * xi);
                        f_out[((size_t)p * nq + q) * 3 + l31] = (oa[r] + b3v) * mask;
                    }
                }
            }
        }
    }
}

// ---------------- aux: prop passthrough + xi fill ----------------
__global__ void aux_kernel(const float* __restrict__ prop, float* __restrict__ out_p,
                           float* __restrict__ out_xi, int EC, int nq, float inv)
{
    int i = blockIdx.x * blockDim.x + threadIdx.x;
    if (i < EC) out_p[i] = prop[i];
    if (i < EC * nq) out_xi[i] = (float)(i % nq) * inv;
}

extern "C" void kernel_launch(void* const* d_in, const int* in_sizes, int n_in,
                              void* d_out, int out_size, void* d_ws, size_t ws_size,
                              hipStream_t stream) {
    const float* x     = (const float*)d_in[0];
    const int*   ei    = (const int*)d_in[1];
    const float* ea    = (const float*)d_in[2];
    const int*   conn  = (const int*)d_in[3];
    const float* bc    = (const float*)d_in[4];
    const float* prop  = (const float*)d_in[5];
    const float* encW1 = (const float*)d_in[7];
    const float* encb1 = (const float*)d_in[8];
    const float* encW2 = (const float*)d_in[9];
    const float* encb2 = (const float*)d_in[10];
    const float* msgW1 = (const float*)d_in[11];
    const float* msgb1 = (const float*)d_in[12];
    const float* msgW2 = (const float*)d_in[13];
    const float* msgb2 = (const float*)d_in[14];
    const float* updW  = (const float*)d_in[15];
    const float* updb  = (const float*)d_in[16];
    const float* efW1  = (const float*)d_in[17];
    const float* efb1  = (const float*)d_in[18];
    const float* efW2  = (const float*)d_in[19];
    const float* efb2  = (const float*)d_in[20];
    const float* efW3  = (const float*)d_in[21];
    const float* efb3  = (const float*)d_in[22];

    int N  = in_sizes[0] / 9;
    int E  = in_sizes[1] / 2;
    int EC = in_sizes[5];
    int nl = in_sizes[11] / (MSG_IN * HID);
    int nq = (int)(((long long)out_size - (long long)N * HID - EC) / (4LL * EC));

    float* out    = (float*)d_out;
    float* h      = out;
    float* out_xi = out + (size_t)N * HID;
    float* out_f  = out_xi + (size_t)EC * nq;
    float* out_p  = out_f + (size_t)EC * nq * 3;

    // ws: [weights][hb][agg][icnt N][icur N][btot 1024][eord E][srcs_s E][dsts_s E][ea_s 16E]
    size_t w1t_e = (size_t)nl * 128 * KCAP;
    size_t w2t_e = (size_t)nl * 128 * HID;
    size_t updwt_e = (size_t)nl * 128 * 256;
    size_t efw1t_e = 64 * 256, efw2t_e = 64 * 64, efw3t_e = 32 * 64;
    short* w1t   = (short*)d_ws;
    short* w2t   = w1t + w1t_e;
    short* updwt = w2t + w2t_e;
    short* efw1t = updwt + updwt_e;
    short* efw2t = efw1t + efw1t_e;
    short* efw3t = efw2t + efw2t_e;
    size_t wbytes = (w1t_e + w2t_e + updwt_e + efw1t_e + efw2t_e + efw3t_e) * 2;
    wbytes = (wbytes + 255) & ~(size_t)255;
    size_t hb_bytes  = (size_t)N * HID * 2;
    size_t agg_bytes = (size_t)N * HID * 4;
    size_t sort_bytes = ((size_t)2 * N + 1024 + (size_t)3 * E) * 4 + (size_t)E * 32;

    short* hb = nullptr;
    float* agg;
    int *icnt = nullptr, *icur = nullptr, *btot = nullptr, *eord = nullptr;
    int *srcs_s = nullptr, *dsts_s = nullptr;
    short* ea_s = nullptr;
    if (ws_size >= wbytes + hb_bytes + agg_bytes + sort_bytes) {
        char* p = (char*)d_ws + wbytes;
        hb = (short*)p;      p += hb_bytes;
        agg = (float*)p;     p += agg_bytes;
        icnt = (int*)p;      p += (size_t)N * 4;
        icur = (int*)p;      p += (size_t)N * 4;
        btot = (int*)p;      p += 1024 * 4;
        eord = (int*)p;      p += (size_t)E * 4;
        srcs_s = (int*)p;    p += (size_t)E * 4;
        dsts_s = (int*)p;    p += (size_t)E * 4;
        ea_s = (short*)p;
    } else if (ws_size >= wbytes + hb_bytes + agg_bytes) {
        hb  = (short*)((char*)d_ws + wbytes);
        agg = (float*)((char*)d_ws + wbytes + hb_bytes);
    } else {
        agg = (float*)((char*)d_ws + wbytes);
    }

    hipFuncSetAttribute((const void*)msg_mfma_kernel,
                        hipFuncAttributeMaxDynamicSharedMemorySize, MSG_LDS);

    encoder_kernel<<<N, 128, 0, stream>>>(x, encW1, encb1, encW2, encb2, h, hb);

    {
        int chunks = nl * 128 * (KCAP / 8) + nl * 128 * (HID / 8) + nl * 128 * 32
                   + 64 * 32 + 64 * 8 + 32 * 8;
        convert_w_kernel<<<(chunks + 255) / 256, 256, 0, stream>>>(
            msgW1, msgW2, updW, efW1, efW2, efW3,
            w1t, w2t, updwt, efw1t, efw2t, efw3t, nl);
    }

    if (ea_s) {
        int nb = (N + 255) / 256;
        hipMemsetAsync(icnt, 0, (size_t)N * 4, stream);
        hist_kernel<<<512, 256, 0, stream>>>(ei, icnt, E);
        scanA_kernel<<<nb, 256, 0, stream>>>(icnt, btot, N);
        scanB_kernel<<<1, 1024, 0, stream>>>(btot, nb);
        scanC_kernel<<<nb, 256, 0, stream>>>(icnt, btot, icur, N);
        scatter_kernel<<<512, 256, 0, stream>>>(ei, icur, eord, E);
        reorder_kernel<<<512, 256, 0, stream>>>(ei, ea, eord, srcs_s, dsts_s, ea_s, E);
    }

    int ntiles = (E + TILE_E - 1) / TILE_E;
    int utiles = (N + 63) / 64;
    for (int l = 0; l < nl; ++l) {
        hipMemsetAsync(agg, 0, agg_bytes, stream);
        msg_mfma_kernel<<<256, 512, MSG_LDS, stream>>>(
            h, hb, ei, ea, srcs_s, dsts_s, ea_s,
            w1t + (size_t)l * 128 * KCAP, msgb1 + (size_t)l * HID,
            w2t + (size_t)l * 128 * HID,  msgb2 + (size_t)l * HID,
            agg, E, ntiles);
        upd_mfma_kernel<<<512, 256, 0, stream>>>(
            h, hb, agg, updwt + (size_t)l * 128 * 256, updb + (size_t)l * HID, N, utiles);
    }

    int ftiles = (EC + 63) / 64;
    fields_mfma_kernel<<<512, 256, 0, stream>>>(
        h, hb, conn, bc, efW1, efb1, efb2, efb3, efw1t, efw2t, efw3t,
        out_f, EC, nq, ftiles);

    float inv = (nq > 1) ? 1.f / (float)(nq - 1) : 0.f;
    aux_kernel<<<(EC * nq + 255) / 256, 256, 0, stream>>>(prop, out_p, out_xi, EC, nq, inv);
}

// Round 15
// 1642.709 us; speedup vs baseline: 1.7823x; 1.0645x over previous
//
#include <hip/hip_runtime.h>
#include <hip/hip_bf16.h>

#define HID 128
#define EA_DIM 11
#define MSG_IN (2 * HID + EA_DIM)   // 267
#define TILE_E 128
#define KCAP 272                     // layer-1 K padded to 17*16
#define KB (KCAP * 2)                // 544 bytes per LDS row
#define MSG_LDS 139264               // W1T (69632) + A1/A2 union (69632)

typedef __attribute__((ext_vector_type(8))) short short8;
typedef __attribute__((ext_vector_type(16))) float f32x16;
typedef __attribute__((ext_vector_type(4))) float float4v;

__device__ __forceinline__ float siluf(float x) { return x / (1.f + __expf(-x)); }
__device__ __forceinline__ short f2bf(float f) {
    __hip_bfloat16 h = __float2bfloat16(f);
    return *reinterpret_cast<short*>(&h);
}
__device__ __forceinline__ float bfbits2f(unsigned short u) {
    return __uint_as_float(((unsigned)u) << 16);
}
__device__ __forceinline__ int crow(int r, int khalf) { return (r & 3) + 8 * (r >> 2) + 4 * khalf; }

// Bijective linear-address swizzle (R13-verified)
__device__ __forceinline__ int swz(int a) { return a ^ (((a >> 7) & 7) << 4); }

// ---------------- encoder ----------------
__global__ __launch_bounds__(128) void encoder_kernel(
    const float* __restrict__ x, const float* __restrict__ W1, const float* __restrict__ b1,
    const float* __restrict__ W2, const float* __restrict__ b2,
    float* __restrict__ h, short* __restrict__ hb)
{
    int i = blockIdx.x, j = threadIdx.x;
    __shared__ float xs[9];
    __shared__ float t1[HID];
    if (j < 9) xs[j] = x[(size_t)i * 9 + j];
    __syncthreads();
    float acc = b1[j];
    #pragma unroll
    for (int k = 0; k < 9; ++k) acc = fmaf(xs[k], W1[k * HID + j], acc);
    t1[j] = siluf(acc);
    __syncthreads();
    float acc2 = b2[j];
    #pragma unroll 8
    for (int k = 0; k < HID; ++k) acc2 = fmaf(t1[k], W2[k * HID + j], acc2);
    float v = siluf(acc2);
    h[(size_t)i * HID + j] = v;
    if (hb) hb[(size_t)i * HID + j] = f2bf(v);
}

// ---- one-time weight conversion to transposed bf16 layouts ----
__global__ void convert_w_kernel(
    const float* __restrict__ msgW1, const float* __restrict__ msgW2,
    const float* __restrict__ updW,
    const float* __restrict__ efW1, const float* __restrict__ efW2, const float* __restrict__ efW3,
    short* __restrict__ w1t, short* __restrict__ w2t, short* __restrict__ updwt,
    short* __restrict__ efw1t, short* __restrict__ efw2t, short* __restrict__ efw3t, int nl)
{
    int gid = blockIdx.x * blockDim.x + threadIdx.x;
    int n1 = nl * 128 * (KCAP / 8);
    int n2 = nl * 128 * (HID / 8);
    int n3 = nl * 128 * 32;
    int n4 = 64 * 32, n5 = 64 * 8, n6 = 32 * 8;
    short8 v;
    if (gid < n1) {
        int c = gid % (KCAP / 8);
        int rem = gid / (KCAP / 8);
        int n = rem % 128, lay = rem / 128;
        #pragma unroll
        for (int j = 0; j < 8; ++j) {
            int k = c * 8 + j;
            v[j] = (k < MSG_IN) ? f2bf(msgW1[(size_t)lay * MSG_IN * HID + (size_t)k * HID + n]) : (short)0;
        }
        *(short8*)(w1t + ((size_t)lay * 128 + n) * KCAP + c * 8) = v;
    } else if (gid < n1 + n2) {
        int g = gid - n1;
        int c = g % (HID / 8);
        int rem = g / (HID / 8);
        int n = rem % 128, lay = rem / 128;
        #pragma unroll
        for (int j = 0; j < 8; ++j)
            v[j] = f2bf(msgW2[(size_t)lay * HID * HID + (size_t)(c * 8 + j) * HID + n]);
        *(short8*)(w2t + ((size_t)lay * 128 + n) * HID + c * 8) = v;
    } else if (gid < n1 + n2 + n3) {
        int g = gid - n1 - n2;
        int c = g & 31;
        int rem = g >> 5;
        int n = rem & 127, lay = rem >> 7;
        #pragma unroll
        for (int j = 0; j < 8; ++j)
            v[j] = f2bf(updW[(size_t)lay * 256 * 128 + (size_t)(c * 8 + j) * 128 + n]);
        *(short8*)(updwt + ((size_t)lay * 128 + n) * 256 + c * 8) = v;
    } else if (gid < n1 + n2 + n3 + n4) {
        int g = gid - n1 - n2 - n3;
        int c = g & 31, n = g >> 5;
        #pragma unroll
        for (int j = 0; j < 8; ++j)
            v[j] = f2bf(efW1[(size_t)(c * 8 + j + 1) * 64 + n]);
        *(short8*)(efw1t + (size_t)n * 256 + c * 8) = v;
    } else if (gid < n1 + n2 + n3 + n4 + n5) {
        int g = gid - n1 - n2 - n3 - n4;
        int c = g & 7, n = g >> 3;
        #pragma unroll
        for (int j = 0; j < 8; ++j)
            v[j] = f2bf(efW2[(size_t)(c * 8 + j) * 64 + n]);
        *(short8*)(efw2t + (size_t)n * 64 + c * 8) = v;
    } else if (gid < n1 + n2 + n3 + n4 + n5 + n6) {
        int g = gid - n1 - n2 - n3 - n4 - n5;
        int c = g & 7, n = g >> 3;
        #pragma unroll
        for (int j = 0; j < 8; ++j)
            v[j] = (n < 3) ? f2bf(efW3[(size_t)(c * 8 + j) * 3 + n]) : (short)0;
        *(short8*)(efw3t + (size_t)n * 64 + c * 8) = v;
    }
}

// ---------------- CSR sort preprocessing ----------------
__global__ void hist_kernel(const int* __restrict__ ei, int* __restrict__ cnt, int E)
{
    for (int e = blockIdx.x * blockDim.x + threadIdx.x; e < E; e += gridDim.x * blockDim.x)
        atomicAdd(&cnt[ei[(size_t)E + e]], 1);
}
__global__ __launch_bounds__(256) void scanA_kernel(const int* __restrict__ cnt, int* __restrict__ btot, int N)
{
    __shared__ int s[256];
    int i = blockIdx.x * 256 + threadIdx.x;
    s[threadIdx.x] = (i < N) ? cnt[i] : 0;
    __syncthreads();
    for (int o = 128; o > 0; o >>= 1) {
        if (threadIdx.x < o) s[threadIdx.x] += s[threadIdx.x + o];
        __syncthreads();
    }
    if (threadIdx.x == 0) btot[blockIdx.x] = s[0];
}
__global__ __launch_bounds__(1024) void scanB_kernel(int* __restrict__ btot, int nb)
{
    __shared__ int s[1024];
    int t = threadIdx.x;
    int v = (t < nb) ? btot[t] : 0;
    s[t] = v;
    __syncthreads();
    for (int o = 1; o < 1024; o <<= 1) {
        int tv = 0;
        if (t >= o) tv = s[t - o];
        __syncthreads();
        s[t] += tv;
        __syncthreads();
    }
    if (t < nb) btot[t] = s[t] - v;   // exclusive
}
__global__ __launch_bounds__(256) void scanC_kernel(const int* __restrict__ cnt, const int* __restrict__ btot,
                                                    int* __restrict__ cur, int N)
{
    __shared__ int s[256];
    int i = blockIdx.x * 256 + threadIdx.x;
    int t = threadIdx.x;
    int v = (i < N) ? cnt[i] : 0;
    s[t] = v;
    __syncthreads();
    for (int o = 1; o < 256; o <<= 1) {
        int tv = 0;
        if (t >= o) tv = s[t - o];
        __syncthreads();
        s[t] += tv;
        __syncthreads();
    }
    if (i < N) cur[i] = btot[blockIdx.x] + s[t] - v;   // exclusive start
}
__global__ void scatter_kernel(const int* __restrict__ ei, int* __restrict__ cur,
                               int* __restrict__ eord, int E)
{
    for (int e = blockIdx.x * blockDim.x + threadIdx.x; e < E; e += gridDim.x * blockDim.x) {
        int d = ei[(size_t)E + e];
        int p = atomicAdd(&cur[d], 1);
        eord[p] = e;
    }
}
__global__ void reorder_kernel(const int* __restrict__ ei, const float* __restrict__ ea,
                               const int* __restrict__ eord,
                               int* __restrict__ srcs_s, int* __restrict__ dsts_s,
                               short* __restrict__ ea_s, int E)
{
    for (int p = blockIdx.x * blockDim.x + threadIdx.x; p < E; p += gridDim.x * blockDim.x) {
        int es = eord[p];
        srcs_s[p] = ei[es];
        dsts_s[p] = ei[(size_t)E + es];
        short tv[16];
        #pragma unroll
        for (int j = 0; j < 16; ++j) tv[j] = 0;
        #pragma unroll
        for (int j = 0; j < EA_DIM; ++j) tv[j] = f2bf(ea[(size_t)es * EA_DIM + j]);
        short8 v0, v1;
        #pragma unroll
        for (int j = 0; j < 8; ++j) { v0[j] = tv[j]; v1[j] = tv[8 + j]; }
        *(short8*)(ea_s + (size_t)p * 16) = v0;
        *(short8*)(ea_s + (size_t)p * 16 + 8) = v1;
    }
}

// ======== MFMA message kernel (R14, unchanged: proven 182 µs) ========
__global__ __launch_bounds__(512, 1) void msg_mfma_kernel(
    const float* __restrict__ h, const short* __restrict__ hb,
    const int* __restrict__ ei, const float* __restrict__ ea,
    const int* __restrict__ srcs_s, const int* __restrict__ dsts_s, const short* __restrict__ ea_s,
    const short* __restrict__ w1t, const float* __restrict__ b1,
    const short* __restrict__ w2t, const float* __restrict__ b2,
    float* __restrict__ agg, int E, int ntiles)
{
    extern __shared__ char smem[];       // [W1T 69632 | A1/A2 union 69632]
    char* sA = smem + 69632;
    __shared__ int dsts[TILE_E];

    int tid = threadIdx.x, ln = tid & 63, wave = tid >> 6;
    int mh = wave & 1, nq4 = wave >> 1;        // 2 (M) x 4 (N) waves
    int l31 = ln & 31, khalf = ln >> 5;

    // ---- stage W1T once per block (address-swizzled) ----
    {
        int row = tid & 127, grp = tid >> 7;
        for (int c = grp; c < 34; c += 4) {
            short8 v = *(const short8*)(w1t + (size_t)row * KCAP + c * 8);
            *(short8*)(smem + swz(row * KB + c * 16)) = v;
        }
    }

    int col = nq4 * 32 + l31;                  // this wave's output column
    float b1v = b1[col], b2v = b2[col];
    short8 zer;
    #pragma unroll
    for (int j = 0; j < 8; ++j) zer[j] = 0;
    int ar0 = mh * 64 + l31;                   // A rows (and +32)
    const short8* w2r = (const short8*)(w2t + (size_t)col * HID);

    bool sorted = (ea_s != nullptr) && (hb != nullptr);

    // ---- prefetch state (sorted path): 4 threads per edge row ----
    int pr = tid >> 2, pq = tid & 3;
    int pf_idx = 0; bool pf_valid = false;
    short8 pf_h[8];
    short8 pf_e0 = zer, pf_e1 = zer;

    if (sorted) {
        long ep = (long)blockIdx.x * TILE_E + pr;
        pf_valid = ep < E;
        pf_idx = pf_valid ? ((pq < 2) ? srcs_s[ep] : dsts_s[ep]) : 0;
        const short8* hr8 = (const short8*)(hb + (size_t)pf_idx * HID + (pq & 1) * 64);
        #pragma unroll
        for (int c = 0; c < 8; ++c) pf_h[c] = hr8[c];
        if (pq == 3 && pf_valid) {
            pf_e0 = *(const short8*)(ea_s + (size_t)ep * 16);
            pf_e1 = *(const short8*)(ea_s + (size_t)ep * 16 + 8);
        }
    }

    #pragma unroll 1
    for (int tile = blockIdx.x; tile < ntiles; tile += gridDim.x) {
        __syncthreads();   // b0

        if (sorted) {
            int dbase = (pq >> 1) * 256 + (pq & 1) * 128;
            #pragma unroll
            for (int c = 0; c < 8; ++c) {
                short8 v = pf_valid ? pf_h[c] : zer;
                *(short8*)(sA + swz(pr * KB + dbase + c * 16)) = v;
            }
            if (pq == 2) dsts[pr] = pf_valid ? pf_idx : -1;
            if (pq == 3) {
                *(short8*)(sA + swz(pr * KB + 512)) = pf_valid ? pf_e0 : zer;
                *(short8*)(sA + swz(pr * KB + 528)) = pf_valid ? pf_e1 : zer;
            }
        } else {
            int r = pr, q = pq;
            long ep = (long)tile * TILE_E + r;
            bool valid = ep < E;
            int idx = 0;
            if (valid) idx = (q < 2) ? ei[ep] : ei[(size_t)E + ep];
            int half = q & 1;
            int dbase = (q >> 1) * 256 + half * 128;
            if (hb) {
                const short8* hr8 = (const short8*)(hb + (size_t)idx * HID + half * 64);
                #pragma unroll
                for (int c = 0; c < 8; ++c) {
                    short8 v = valid ? hr8[c] : zer;
                    *(short8*)(sA + swz(r * KB + dbase + c * 16)) = v;
                }
            } else {
                const float* hr = h + (size_t)idx * HID + half * 64;
                #pragma unroll
                for (int c = 0; c < 8; ++c) {
                    short8 v = zer;
                    if (valid) {
                        float4v f0 = *(const float4v*)(hr + c * 8);
                        float4v f1 = *(const float4v*)(hr + c * 8 + 4);
                        #pragma unroll
                        for (int j = 0; j < 4; ++j) { v[j] = f2bf(f0[j]); v[4 + j] = f2bf(f1[j]); }
                    }
                    *(short8*)(sA + swz(r * KB + dbase + c * 16)) = v;
                }
            }
            if (q == 2) dsts[r] = valid ? idx : -1;
            if (q == 3) {
                short8 v0 = zer, v1 = zer;
                if (valid) {
                    short tv[16];
                    #pragma unroll
                    for (int j = 0; j < 16; ++j) tv[j] = 0;
                    #pragma unroll
                    for (int j = 0; j < EA_DIM; ++j) tv[j] = f2bf(ea[(size_t)ep * EA_DIM + j]);
                    #pragma unroll
                    for (int j = 0; j < 8; ++j) { v0[j] = tv[j]; v1[j] = tv[8 + j]; }
                }
                *(short8*)(sA + swz(r * KB + 512)) = v0;
                *(short8*)(sA + swz(r * KB + 528)) = v1;
            }
        }
        __syncthreads();   // b1

        if (sorted) {
            long ep = (long)(tile + gridDim.x) * TILE_E + pr;
            pf_valid = ep < E;
            pf_idx = pf_valid ? ((pq < 2) ? srcs_s[ep] : dsts_s[ep]) : 0;
            const short8* hr8 = (const short8*)(hb + (size_t)pf_idx * HID + (pq & 1) * 64);
            #pragma unroll
            for (int c = 0; c < 8; ++c) pf_h[c] = hr8[c];
            if (pq == 3 && pf_valid) {
                pf_e0 = *(const short8*)(ea_s + (size_t)ep * 16);
                pf_e1 = *(const short8*)(ea_s + (size_t)ep * 16 + 8);
            }
        }

        // ---- layer 1 ----
        f32x16 acc1[2] = {};
        for (int kk = 0; kk < 17; ++kk) {
            int kb = kk * 32 + khalf * 16;
            short8 a0 = *(short8*)(sA + swz(ar0 * KB + kb));
            short8 a1 = *(short8*)(sA + swz((ar0 + 32) * KB + kb));
            short8 w  = *(short8*)(smem + swz(col * KB + kb));
            acc1[0] = __builtin_amdgcn_mfma_f32_32x32x16_bf16(a0, w, acc1[0], 0, 0, 0);
            acc1[1] = __builtin_amdgcn_mfma_f32_32x32x16_bf16(a1, w, acc1[1], 0, 0, 0);
        }
        __syncthreads();   // b2

        // ---- bias + silu -> A2 ----
        #pragma unroll
        for (int mi = 0; mi < 2; ++mi)
            #pragma unroll
            for (int r = 0; r < 16; ++r) {
                float s = siluf(acc1[mi][r] + b1v);
                int row = mh * 64 + mi * 32 + crow(r, khalf);
                *(short*)(sA + ((row * 256 + col * 2) ^ ((row & 7) << 4))) = f2bf(s);
            }
        __syncthreads();   // b3

        // ---- layer 2 ----
        f32x16 acc2[2];
        #pragma unroll
        for (int mi = 0; mi < 2; ++mi)
            #pragma unroll
            for (int r = 0; r < 16; ++r) acc2[mi][r] = b2v;
        for (int kk = 0; kk < 8; ++kk) {
            int kb = kk * 32 + khalf * 16;
            short8 a0 = *(short8*)(sA + ((ar0 * 256 + kb) ^ ((ar0 & 7) << 4)));
            short8 a1 = *(short8*)(sA + (((ar0 + 32) * 256 + kb) ^ (((ar0 + 32) & 7) << 4)));
            short8 w  = w2r[kk * 2 + khalf];
            acc2[0] = __builtin_amdgcn_mfma_f32_32x32x16_bf16(a0, w, acc2[0], 0, 0, 0);
            acc2[1] = __builtin_amdgcn_mfma_f32_32x32x16_bf16(a1, w, acc2[1], 0, 0, 0);
        }

        if (sorted) {
            // ---- in-register run-length dedup + atomic flush ----
            float s = 0.f; int dprev = -1;
            #pragma unroll
            for (int mi = 0; mi < 2; ++mi)
                #pragma unroll
                for (int r = 0; r < 16; ++r) {
                    int row = mh * 64 + mi * 32 + crow(r, khalf);
                    int d = dsts[row];
                    if (d != dprev) {
                        if (dprev >= 0) atomicAdd(agg + (size_t)dprev * HID + col, s);
                        s = 0.f; dprev = d;
                    }
                    if (d >= 0) s += acc2[mi][r];
                }
            if (dprev >= 0) atomicAdd(agg + (size_t)dprev * HID + col, s);
        } else {
            #pragma unroll
            for (int mi = 0; mi < 2; ++mi)
                #pragma unroll
                for (int r = 0; r < 16; ++r) {
                    int row = mh * 64 + mi * 32 + crow(r, khalf);
                    int d = dsts[row];
                    if (d >= 0) atomicAdd(agg + (size_t)d * HID + col, acc2[mi][r]);
                }
        }
    }
}

// ---------------- MFMA update kernel ----------------
// NEW: residual read from LDS-staged hb (no global h read); fp32 h written only
// on the LAST layer; agg rows zeroed inline after staging (replaces per-layer memset).
__global__ __launch_bounds__(256) void upd_mfma_kernel(
    float* __restrict__ h, short* __restrict__ hb, float* __restrict__ agg,
    const short* __restrict__ updwt, const float* __restrict__ b, int N, int ntiles, int lastl)
{
    __shared__ char sA[64 * 512];
    int tid = threadIdx.x, ln = tid & 63, wave = tid >> 6;
    int mhalf = wave & 1, nhalf = wave >> 1, l31 = ln & 31, khalf = ln >> 5;
    float bv[2];
    #pragma unroll
    for (int ni = 0; ni < 2; ++ni) bv[ni] = b[nhalf * 64 + ni * 32 + l31];
    short8 zer;
    #pragma unroll
    for (int j = 0; j < 8; ++j) zer[j] = 0;

    #pragma unroll 1
    for (int tile = blockIdx.x; tile < ntiles; tile += gridDim.x) {
        __syncthreads();
        {
            int r = tid >> 2, q = tid & 3;
            int node = tile * 64 + r;
            bool valid = node < N;
            if (q < 2) {
                if (hb) {
                    const short8* hr8 = (const short8*)(hb + (size_t)node * HID + (q & 1) * 64);
                    #pragma unroll
                    for (int c = 0; c < 8; ++c) {
                        short8 v = valid ? hr8[c] : zer;
                        *(short8*)(sA + ((r * 512 + (q & 1) * 128 + c * 16) ^ ((r & 7) << 4))) = v;
                    }
                } else {
                    const float* hr = h + (size_t)node * HID + (q & 1) * 64;
                    #pragma unroll
                    for (int c = 0; c < 8; ++c) {
                        short8 v = zer;
                        if (valid) {
                            float4v f0 = *(const float4v*)(hr + c * 8);
                            float4v f1 = *(const float4v*)(hr + c * 8 + 4);
                            #pragma unroll
                            for (int j = 0; j < 4; ++j) { v[j] = f2bf(f0[j]); v[4 + j] = f2bf(f1[j]); }
                        }
                        *(short8*)(sA + ((r * 512 + (q & 1) * 128 + c * 16) ^ ((r & 7) << 4))) = v;
                    }
                }
            } else {
                float* ar = agg + (size_t)node * HID + (q & 1) * 64;
                float4v z = {0.f, 0.f, 0.f, 0.f};
                #pragma unroll
                for (int c = 0; c < 8; ++c) {
                    short8 v = zer;
                    if (valid) {
                        float4v f0 = *(const float4v*)(ar + c * 8);
                        float4v f1 = *(const float4v*)(ar + c * 8 + 4);
                        #pragma unroll
                        for (int j = 0; j < 4; ++j) { v[j] = f2bf(f0[j]); v[4 + j] = f2bf(f1[j]); }
                    }
                    *(short8*)(sA + ((r * 512 + 256 + (q & 1) * 128 + c * 16) ^ ((r & 7) << 4))) = v;
                }
                if (valid) {
                    // zero agg for the next layer (replaces per-layer memset)
                    #pragma unroll
                    for (int c = 0; c < 8; ++c) {
                        *(float4v*)(ar + c * 8) = z;
                        *(float4v*)(ar + c * 8 + 4) = z;
                    }
                }
            }
        }
        __syncthreads();
        f32x16 acc[2] = {};
        int arow = mhalf * 32 + l31;
        const short* bp0 = updwt + (size_t)(nhalf * 64 + l31) * 256 + khalf * 8;
        const short* bp1 = updwt + (size_t)(nhalf * 64 + 32 + l31) * 256 + khalf * 8;
        for (int kk = 0; kk < 16; ++kk) {
            short8 a  = *(short8*)(sA + ((arow * 512 + kk * 32 + khalf * 16) ^ ((arow & 7) << 4)));
            short8 w0 = *(const short8*)(bp0 + kk * 16);
            short8 w1 = *(const short8*)(bp1 + kk * 16);
            acc[0] = __builtin_amdgcn_mfma_f32_32x32x16_bf16(a, w0, acc[0], 0, 0, 0);
            acc[1] = __builtin_amdgcn_mfma_f32_32x32x16_bf16(a, w1, acc[1], 0, 0, 0);
        }
        #pragma unroll
        for (int ni = 0; ni < 2; ++ni) {
            int col = nhalf * 64 + ni * 32 + l31;
            #pragma unroll
            for (int r = 0; r < 16; ++r) {
                int rloc = mhalf * 32 + crow(r, khalf);
                int node = tile * 64 + rloc;
                if (node < N) {
                    float hprev;
                    if (hb) {
                        unsigned short u = *(unsigned short*)(sA + ((rloc * 512 + col * 2) ^ ((rloc & 7) << 4)));
                        hprev = bfbits2f(u);
                    } else {
                        hprev = h[(size_t)node * HID + col];
                    }
                    float val = siluf(acc[ni][r] + bv[ni] + hprev);
                    if (hb) {
                        hb[(size_t)node * HID + col] = f2bf(val);
                        if (lastl) h[(size_t)node * HID + col] = val;
                    } else {
                        h[(size_t)node * HID + col] = val;
                    }
                }
            }
        }
    }
}

// ---------------- MFMA edge-fields kernel ----------------
__global__ __launch_bounds__(256) void fields_mfma_kernel(
    const float* __restrict__ h, const short* __restrict__ hb,
    const int* __restrict__ conn, const float* __restrict__ bc,
    const float* __restrict__ efW1, const float* __restrict__ efb1,
    const float* __restrict__ efb2, const float* __restrict__ efb3,
    const short* __restrict__ efw1t, const short* __restrict__ efw2t, const short* __restrict__ efw3t,
    float* __restrict__ f_out, int EC, int nq, int ntiles)
{
    __shared__ char sA1[64 * 512];
    __shared__ char sA2[64 * 128];
    __shared__ char sF2[64 * 128];
    __shared__ float bcis[64], bcjs[64];
    int tid = threadIdx.x, ln = tid & 63, wave = tid >> 6;
    int mhalf = wave & 1, nhalf = wave >> 1, l31 = ln & 31, khalf = ln >> 5;
    int col = nhalf * 32 + l31;
    float w1x = efW1[col];
    float b1v = efb1[col], b2v = efb2[col];
    float b3v = (l31 < 3) ? efb3[l31] : 0.f;
    float inv = (nq > 1) ? 1.f / (float)(nq - 1) : 0.f;
    short8 zer;
    #pragma unroll
    for (int j = 0; j < 8; ++j) zer[j] = 0;

    #pragma unroll 1
    for (int tile = blockIdx.x; tile < ntiles; tile += gridDim.x) {
        __syncthreads();
        {
            int r = tid >> 2, q = tid & 3;
            long p = (long)tile * 64 + r;
            bool valid = p < EC;
            int node = 0;
            if (valid) node = conn[p * 2 + (q >> 1)];
            if (q == 0) {
                bcis[r] = valid ? bc[conn[p * 2]] : 0.f;
                bcjs[r] = valid ? bc[conn[p * 2 + 1]] : 0.f;
            }
            int cbyte = (q >> 1) * 256 + (q & 1) * 128;
            if (hb) {
                const short8* hr8 = (const short8*)(hb + (size_t)node * HID + (q & 1) * 64);
                #pragma unroll
                for (int c = 0; c < 8; ++c) {
                    short8 v = valid ? hr8[c] : zer;
                    *(short8*)(sA1 + ((r * 512 + cbyte + c * 16) ^ ((r & 7) << 4))) = v;
                }
            } else {
                const float* hr = h + (size_t)node * HID + (q & 1) * 64;
                #pragma unroll
                for (int c = 0; c < 8; ++c) {
                    short8 v = zer;
                    if (valid) {
                        float4v f0 = *(const float4v*)(hr + c * 8);
                        float4v f1 = *(const float4v*)(hr + c * 8 + 4);
                        #pragma unroll
                        for (int j = 0; j < 4; ++j) { v[j] = f2bf(f0[j]); v[4 + j] = f2bf(f1[j]); }
                    }
                    *(short8*)(sA1 + ((r * 512 + cbyte + c * 16) ^ ((r & 7) << 4))) = v;
                }
            }
        }
        __syncthreads();
        f32x16 hp = {};
        int arow = mhalf * 32 + l31;
        for (int kk = 0; kk < 16; ++kk) {
            short8 a = *(short8*)(sA1 + ((arow * 512 + kk * 32 + khalf * 16) ^ ((arow & 7) << 4)));
            short8 b = *(const short8*)(efw1t + (size_t)col * 256 + kk * 16 + khalf * 8);
            hp = __builtin_amdgcn_mfma_f32_32x32x16_bf16(a, b, hp, 0, 0, 0);
        }
        #pragma unroll
        for (int r = 0; r < 16; ++r) hp[r] += b1v;

        for (int q = 0; q < nq; ++q) {
            float xi = (float)q * inv;
            #pragma unroll
            for (int r = 0; r < 16; ++r) {
                float f1 = siluf(fmaf(xi, w1x, hp[r]));
                int row = mhalf * 32 + crow(r, khalf);
                *(short*)(sA2 + ((row * 128 + col * 2) ^ ((row & 7) << 4))) = f2bf(f1);
            }
            __syncthreads();
            f32x16 f2a = {};
            for (int kk = 0; kk < 4; ++kk) {
                short8 a = *(short8*)(sA2 + ((arow * 128 + kk * 32 + khalf * 16) ^ ((l31 & 7) << 4)));
                short8 b = *(const short8*)(efw2t + (size_t)col * 64 + kk * 16 + khalf * 8);
                f2a = __builtin_amdgcn_mfma_f32_32x32x16_bf16(a, b, f2a, 0, 0, 0);
            }
            #pragma unroll
            for (int r = 0; r < 16; ++r) {
                float f2 = siluf(f2a[r] + b2v);
                int row = mhalf * 32 + crow(r, khalf);
                *(short*)(sF2 + ((row * 128 + col * 2) ^ ((row & 7) << 4))) = f2bf(f2);
            }
            __syncthreads();
            f32x16 oa = {};
            for (int kk = 0; kk < 4; ++kk) {
                short8 a = *(short8*)(sF2 + ((arow * 128 + kk * 32 + khalf * 16) ^ ((l31 & 7) << 4)));
                short8 b = *(const short8*)(efw3t + (size_t)l31 * 64 + kk * 16 + khalf * 8);
                oa = __builtin_amdgcn_mfma_f32_32x32x16_bf16(a, b, oa, 0, 0, 0);
            }
            if (nhalf == 0 && l31 < 3) {
                #pragma unroll
                for (int r = 0; r < 16; ++r) {
                    int row = mhalf * 32 + crow(r, khalf);
                    long p = (long)tile * 64 + row;
                    if (p < EC) {
                        float mask = (1.f - bcis[row] * (1.f - xi)) * (1.f - bcjs[row] * xi);
                        f_out[((size_t)p * nq + q) * 3 + l31] = (oa[r] + b3v) * mask;
                    }
                }
            }
        }
    }
}

// ---------------- aux: prop passthrough + xi fill ----------------
__global__ void aux_kernel(const float* __restrict__ prop, float* __restrict__ out_p,
                           float* __restrict__ out_xi, int EC, int nq, float inv)
{
    int i = blockIdx.x * blockDim.x + threadIdx.x;
    if (i < EC) out_p[i] = prop[i];
    if (i < EC * nq) out_xi[i] = (float)(i % nq) * inv;
}

extern "C" void kernel_launch(void* const* d_in, const int* in_sizes, int n_in,
                              void* d_out, int out_size, void* d_ws, size_t ws_size,
                              hipStream_t stream) {
    const float* x     = (const float*)d_in[0];
    const int*   ei    = (const int*)d_in[1];
    const float* ea    = (const float*)d_in[2];
    const int*   conn  = (const int*)d_in[3];
    const float* bc    = (const float*)d_in[4];
    const float* prop  = (const float*)d_in[5];
    const float* encW1 = (const float*)d_in[7];
    const float* encb1 = (const float*)d_in[8];
    const float* encW2 = (const float*)d_in[9];
    const float* encb2 = (const float*)d_in[10];
    const float* msgW1 = (const float*)d_in[11];
    const float* msgb1 = (const float*)d_in[12];
    const float* msgW2 = (const float*)d_in[13];
    const float* msgb2 = (const float*)d_in[14];
    const float* updW  = (const float*)d_in[15];
    const float* updb  = (const float*)d_in[16];
    const float* efW1  = (const float*)d_in[17];
    const float* efb1  = (const float*)d_in[18];
    const float* efW2  = (const float*)d_in[19];
    const float* efb2  = (const float*)d_in[20];
    const float* efW3  = (const float*)d_in[21];
    const float* efb3  = (const float*)d_in[22];

    int N  = in_sizes[0] / 9;
    int E  = in_sizes[1] / 2;
    int EC = in_sizes[5];
    int nl = in_sizes[11] / (MSG_IN * HID);
    int nq = (int)(((long long)out_size - (long long)N * HID - EC) / (4LL * EC));

    float* out    = (float*)d_out;
    float* h      = out;
    float* out_xi = out + (size_t)N * HID;
    float* out_f  = out_xi + (size_t)EC * nq;
    float* out_p  = out_f + (size_t)EC * nq * 3;

    // ws: [weights][hb][agg][icnt N][icur N][btot 1024][eord E][srcs_s E][dsts_s E][ea_s 16E]
    size_t w1t_e = (size_t)nl * 128 * KCAP;
    size_t w2t_e = (size_t)nl * 128 * HID;
    size_t updwt_e = (size_t)nl * 128 * 256;
    size_t efw1t_e = 64 * 256, efw2t_e = 64 * 64, efw3t_e = 32 * 64;
    short* w1t   = (short*)d_ws;
    short* w2t   = w1t + w1t_e;
    short* updwt = w2t + w2t_e;
    short* efw1t = updwt + updwt_e;
    short* efw2t = efw1t + efw1t_e;
    short* efw3t = efw2t + efw2t_e;
    size_t wbytes = (w1t_e + w2t_e + updwt_e + efw1t_e + efw2t_e + efw3t_e) * 2;
    wbytes = (wbytes + 255) & ~(size_t)255;
    size_t hb_bytes  = (size_t)N * HID * 2;
    size_t agg_bytes = (size_t)N * HID * 4;
    size_t sort_bytes = ((size_t)2 * N + 1024 + (size_t)3 * E) * 4 + (size_t)E * 32;

    short* hb = nullptr;
    float* agg;
    int *icnt = nullptr, *icur = nullptr, *btot = nullptr, *eord = nullptr;
    int *srcs_s = nullptr, *dsts_s = nullptr;
    short* ea_s = nullptr;
    if (ws_size >= wbytes + hb_bytes + agg_bytes + sort_bytes) {
        char* p = (char*)d_ws + wbytes;
        hb = (short*)p;      p += hb_bytes;
        agg = (float*)p;     p += agg_bytes;
        icnt = (int*)p;      p += (size_t)N * 4;
        icur = (int*)p;      p += (size_t)N * 4;
        btot = (int*)p;      p += 1024 * 4;
        eord = (int*)p;      p += (size_t)E * 4;
        srcs_s = (int*)p;    p += (size_t)E * 4;
        dsts_s = (int*)p;    p += (size_t)E * 4;
        ea_s = (short*)p;
    } else if (ws_size >= wbytes + hb_bytes + agg_bytes) {
        hb  = (short*)((char*)d_ws + wbytes);
        agg = (float*)((char*)d_ws + wbytes + hb_bytes);
    } else {
        agg = (float*)((char*)d_ws + wbytes);
    }

    hipFuncSetAttribute((const void*)msg_mfma_kernel,
                        hipFuncAttributeMaxDynamicSharedMemorySize, MSG_LDS);

    encoder_kernel<<<N, 128, 0, stream>>>(x, encW1, encb1, encW2, encb2, h, hb);

    {
        int chunks = nl * 128 * (KCAP / 8) + nl * 128 * (HID / 8) + nl * 128 * 32
                   + 64 * 32 + 64 * 8 + 32 * 8;
        convert_w_kernel<<<(chunks + 255) / 256, 256, 0, stream>>>(
            msgW1, msgW2, updW, efW1, efW2, efW3,
            w1t, w2t, updwt, efw1t, efw2t, efw3t, nl);
    }

    if (ea_s) {
        int nb = (N + 255) / 256;
        hipMemsetAsync(icnt, 0, (size_t)N * 4, stream);
        hist_kernel<<<512, 256, 0, stream>>>(ei, icnt, E);
        scanA_kernel<<<nb, 256, 0, stream>>>(icnt, btot, N);
        scanB_kernel<<<1, 1024, 0, stream>>>(btot, nb);
        scanC_kernel<<<nb, 256, 0, stream>>>(icnt, btot, icur, N);
        scatter_kernel<<<512, 256, 0, stream>>>(ei, icur, eord, E);
        reorder_kernel<<<512, 256, 0, stream>>>(ei, ea, eord, srcs_s, dsts_s, ea_s, E);
    }

    int ntiles = (E + TILE_E - 1) / TILE_E;
    int utiles = (N + 63) / 64;
    hipMemsetAsync(agg, 0, agg_bytes, stream);   // once; upd re-zeroes per layer
    for (int l = 0; l < nl; ++l) {
        msg_mfma_kernel<<<256, 512, MSG_LDS, stream>>>(
            h, hb, ei, ea, srcs_s, dsts_s, ea_s,
            w1t + (size_t)l * 128 * KCAP, msgb1 + (size_t)l * HID,
            w2t + (size_t)l * 128 * HID,  msgb2 + (size_t)l * HID,
            agg, E, ntiles);
        upd_mfma_kernel<<<512, 256, 0, stream>>>(
            h, hb, agg, updwt + (size_t)l * 128 * 256, updb + (size_t)l * HID, N, utiles,
            (l == nl - 1) ? 1 : 0);
    }

    int ftiles = (EC + 63) / 64;
    fields_mfma_kernel<<<512, 256, 0, stream>>>(
        h, hb, conn, bc, efW1, efb1, efb2, efb3, efw1t, efw2t, efw3t,
        out_f, EC, nq, ftiles);

    float inv = (nq > 1) ? 1.f / (float)(nq - 1) : 0.f;
    aux_kernel<<<(EC * nq + 255) / 256, 256, 0, stream>>>(prop, out_p, out_xi, EC, nq, inv);
}